// Round 3
// baseline (2607.258 us; speedup 1.0000x reference)
//
#include <hip/hip_runtime.h>
#include <hip/hip_bf16.h>
#include <cmath>

using bf16 = __hip_bfloat16;
typedef __bf16 v8bf __attribute__((ext_vector_type(8)));
typedef float  v4f  __attribute__((ext_vector_type(4)));

__device__ __forceinline__ float bf2f(bf16 x) { return __bfloat162float(x); }
__device__ __forceinline__ bf16  f2bf(float x) { return __float2bfloat16(x); }

// flag-aware input load: isf32 ? fp32 : bf16 (element index i from base p)
__device__ __forceinline__ float ldin(const void* p, size_t i, int isf32) {
    if (isf32) return ((const float*)p)[i];
    return bf2f(((const bf16*)p)[i]);
}

__device__ __forceinline__ float wave_sum(float v) {
#pragma unroll
    for (int o = 32; o > 0; o >>= 1) v += __shfl_xor(v, o, 64);
    return v;
}
__device__ __forceinline__ float wave_max(float v) {
#pragma unroll
    for (int o = 32; o > 0; o >>= 1) v = fmaxf(v, __shfl_xor(v, o, 64));
    return v;
}
__device__ __forceinline__ float block_sum(float v, float* sm) {
    v = wave_sum(v);
    int lane = threadIdx.x & 63, w = threadIdx.x >> 6;
    __syncthreads();
    if (lane == 0) sm[w] = v;
    __syncthreads();
    return (sm[0] + sm[1]) + (sm[2] + sm[3]);
}
__device__ __forceinline__ float block_max(float v, float* sm) {
    v = wave_max(v);
    int lane = threadIdx.x & 63, w = threadIdx.x >> 6;
    __syncthreads();
    if (lane == 0) sm[w] = v;
    __syncthreads();
    return fmaxf(fmaxf(sm[0], sm[1]), fmaxf(sm[2], sm[3]));
}

// ---------------- dtype detector: bf16 N(0,1) has no exponents >= 147;
// fp32 read as ushort halves has ~37% garbage-exponent low halves ------------
__global__ void detect_k(const unsigned short* __restrict__ x, int* __restrict__ flag)
{
    __shared__ int s;
    int t = threadIdx.x;
    if (t == 0) s = 0;
    __syncthreads();
    int bad = 0;
    for (int i = t; i < 4096; i += 256) {
        int e = (x[i] >> 7) & 0xFF;
        if (e >= 147) bad++;
    }
    atomicAdd(&s, bad);
    __syncthreads();
    if (t == 0) *flag = (s > 64) ? 1 : 0;
}

// ---------------- MFMA GEMM: C[M,N] = A[M,K] @ BT[N,K]^T, bf16 in, bf16 out --
__global__ __launch_bounds__(256)
void gemm_bt(const bf16* __restrict__ A, const bf16* __restrict__ BT,
             bf16* __restrict__ C, int M, int N, int K, int lda)
{
    __shared__ bf16 As[128 * 32];
    __shared__ bf16 Bs[128 * 32];
    const int t = threadIdx.x;
    const int lane = t & 63;
    const int wave = t >> 6;
    const int wm = (wave >> 1) * 64;
    const int wn = (wave & 1) * 64;
    const int bm = blockIdx.x * 128;
    const int bn = blockIdx.y * 128;
    const int fr = lane & 15;
    const int fk = (lane >> 4) * 8;

    v4f acc[4][4];
#pragma unroll
    for (int i = 0; i < 4; ++i)
#pragma unroll
        for (int j = 0; j < 4; ++j) { v4f z = {0.f, 0.f, 0.f, 0.f}; acc[i][j] = z; }

    for (int k0 = 0; k0 < K; k0 += 32) {
#pragma unroll
        for (int r = 0; r < 2; ++r) {
            int c = t + 256 * r;
            int row = c >> 2;
            int koff = (c & 3) * 8;
            *(int4*)(&As[row * 32 + koff]) =
                *(const int4*)(A + (size_t)(bm + row) * lda + k0 + koff);
            *(int4*)(&Bs[row * 32 + koff]) =
                *(const int4*)(BT + (size_t)(bn + row) * K + k0 + koff);
        }
        __syncthreads();
        v8bf af[4], bfr[4];
#pragma unroll
        for (int mt = 0; mt < 4; ++mt)
            af[mt] = *(const v8bf*)(&As[(wm + mt * 16 + fr) * 32 + fk]);
#pragma unroll
        for (int nt = 0; nt < 4; ++nt)
            bfr[nt] = *(const v8bf*)(&Bs[(wn + nt * 16 + fr) * 32 + fk]);
#pragma unroll
        for (int mt = 0; mt < 4; ++mt)
#pragma unroll
            for (int nt = 0; nt < 4; ++nt)
                acc[mt][nt] = __builtin_amdgcn_mfma_f32_16x16x32_bf16(
                    af[mt], bfr[nt], acc[mt][nt], 0, 0, 0);
        __syncthreads();
    }
    const int r0 = (lane >> 4) * 4;
#pragma unroll
    for (int mt = 0; mt < 4; ++mt)
#pragma unroll
        for (int nt = 0; nt < 4; ++nt)
#pragma unroll
            for (int r = 0; r < 4; ++r) {
                int row = bm + wm + mt * 16 + r0 + r;
                int col = bn + wn + nt * 16 + fr;
                C[(size_t)row * N + col] = f2bf(acc[mt][nt][r]);
            }
}

// ---- same GEMM but output dtype chosen by flag: f32 when flag=1, else bf16 --
__global__ __launch_bounds__(256)
void gemm_bt_out(const bf16* __restrict__ A, const bf16* __restrict__ BT,
                 void* __restrict__ C, int M, int N, int K, int lda,
                 const int* __restrict__ flag)
{
    __shared__ bf16 As[128 * 32];
    __shared__ bf16 Bs[128 * 32];
    const int f = *flag;
    const int t = threadIdx.x;
    const int lane = t & 63;
    const int wave = t >> 6;
    const int wm = (wave >> 1) * 64;
    const int wn = (wave & 1) * 64;
    const int bm = blockIdx.x * 128;
    const int bn = blockIdx.y * 128;
    const int fr = lane & 15;
    const int fk = (lane >> 4) * 8;

    v4f acc[4][4];
#pragma unroll
    for (int i = 0; i < 4; ++i)
#pragma unroll
        for (int j = 0; j < 4; ++j) { v4f z = {0.f, 0.f, 0.f, 0.f}; acc[i][j] = z; }

    for (int k0 = 0; k0 < K; k0 += 32) {
#pragma unroll
        for (int r = 0; r < 2; ++r) {
            int c = t + 256 * r;
            int row = c >> 2;
            int koff = (c & 3) * 8;
            *(int4*)(&As[row * 32 + koff]) =
                *(const int4*)(A + (size_t)(bm + row) * lda + k0 + koff);
            *(int4*)(&Bs[row * 32 + koff]) =
                *(const int4*)(BT + (size_t)(bn + row) * K + k0 + koff);
        }
        __syncthreads();
        v8bf af[4], bfr[4];
#pragma unroll
        for (int mt = 0; mt < 4; ++mt)
            af[mt] = *(const v8bf*)(&As[(wm + mt * 16 + fr) * 32 + fk]);
#pragma unroll
        for (int nt = 0; nt < 4; ++nt)
            bfr[nt] = *(const v8bf*)(&Bs[(wn + nt * 16 + fr) * 32 + fk]);
#pragma unroll
        for (int mt = 0; mt < 4; ++mt)
#pragma unroll
            for (int nt = 0; nt < 4; ++nt)
                acc[mt][nt] = __builtin_amdgcn_mfma_f32_16x16x32_bf16(
                    af[mt], bfr[nt], acc[mt][nt], 0, 0, 0);
        __syncthreads();
    }
    const int r0 = (lane >> 4) * 4;
#pragma unroll
    for (int mt = 0; mt < 4; ++mt)
#pragma unroll
        for (int nt = 0; nt < 4; ++nt)
#pragma unroll
            for (int r = 0; r < 4; ++r) {
                int row = bm + wm + mt * 16 + r0 + r;
                int col = bn + wn + nt * 16 + fr;
                if (f) ((float*)C)[(size_t)row * N + col] = acc[mt][nt][r];
                else   ((bf16*)C)[(size_t)row * N + col] = f2bf(acc[mt][nt][r]);
            }
}

// ---------------- transpose + dtype-cast: out[z][c][r] = in[z][r][c] ---------
__global__ __launch_bounds__(256)
void transpose_k(const void* __restrict__ in, bf16* __restrict__ out, int R, int C,
                 const int* __restrict__ flag)
{
    __shared__ bf16 tile[32][33];
    int f = *flag;
    size_t zoff = (size_t)blockIdx.z * R * C;
    bf16* dst = out + zoff;
    int c0 = blockIdx.x * 32, r0 = blockIdx.y * 32;
    int tx = threadIdx.x, ty = threadIdx.y;
#pragma unroll
    for (int i = 0; i < 32; i += 8)
        tile[ty + i][tx] = f2bf(ldin(in, zoff + (size_t)(r0 + ty + i) * C + c0 + tx, f));
    __syncthreads();
#pragma unroll
    for (int i = 0; i < 32; i += 8)
        dst[(size_t)(c0 + ty + i) * R + r0 + tx] = tile[tx][ty + i];
}

// ---------------- LayerNorm (D=512), x fp32 -> out bf16 ----------------------
__global__ __launch_bounds__(256)
void ln_k(const float* __restrict__ x, const void* __restrict__ g, int goff,
          const int* __restrict__ flag, bf16* __restrict__ out)
{
    __shared__ float sm[4];
    int f = *flag;
    int row = blockIdx.x, t = threadIdx.x;
    const float* xr = x + (size_t)row * 512;
    float v0 = xr[t], v1 = xr[t + 256];
    float mean = block_sum(v0 + v1, sm) * (1.f / 512.f);
    float d0 = v0 - mean, d1 = v1 - mean;
    float var = block_sum(d0 * d0 + d1 * d1, sm) * (1.f / 512.f);
    float rstd = rsqrtf(var + 1e-5f);
    out[(size_t)row * 512 + t]       = f2bf(d0 * rstd * ldin(g, goff + t, f));
    out[(size_t)row * 512 + t + 256] = f2bf(d1 * rstd * ldin(g, goff + t + 256, f));
}

// ---------------- x += LN(t) -------------------------------------------------
__global__ __launch_bounds__(256)
void addln_k(const bf16* __restrict__ tin, const void* __restrict__ g, int goff,
             const int* __restrict__ flag, float* __restrict__ x)
{
    __shared__ float sm[4];
    int f = *flag;
    int row = blockIdx.x, t = threadIdx.x;
    const bf16* tr = tin + (size_t)row * 512;
    float v0 = bf2f(tr[t]), v1 = bf2f(tr[t + 256]);
    float mean = block_sum(v0 + v1, sm) * (1.f / 512.f);
    float d0 = v0 - mean, d1 = v1 - mean;
    float var = block_sum(d0 * d0 + d1 * d1, sm) * (1.f / 512.f);
    float rstd = rsqrtf(var + 1e-5f);
    x[(size_t)row * 512 + t]       += d0 * rstd * ldin(g, goff + t, f);
    x[(size_t)row * 512 + t + 256] += d1 * rstd * ldin(g, goff + t + 256, f);
}

// ---------------- final stable LN --------------------------------------------
__global__ __launch_bounds__(256)
void finln_k(const float* __restrict__ x, const void* __restrict__ g,
             const int* __restrict__ flag, bf16* __restrict__ out)
{
    __shared__ float sm[4];
    int f = *flag;
    int row = blockIdx.x, t = threadIdx.x;
    const float* xr = x + (size_t)row * 512;
    float v0 = xr[t], v1 = xr[t + 256];
    float mx = block_max(fmaxf(v0, v1), sm);
    v0 /= mx; v1 /= mx;
    float mean = block_sum(v0 + v1, sm) * (1.f / 512.f);
    float d0 = v0 - mean, d1 = v1 - mean;
    float var = block_sum(d0 * d0 + d1 * d1, sm) * (1.f / 512.f);
    float rstd = rsqrtf(var + 1e-5f);
    out[(size_t)row * 512 + t]       = f2bf(d0 * rstd * ldin(g, t, f));
    out[(size_t)row * 512 + t + 256] = f2bf(d1 * rstd * ldin(g, t + 256, f));
}

// ---------------- misc elementwise -------------------------------------------
__global__ __launch_bounds__(256)
void x_init(const void* __restrict__ in, const int* __restrict__ flag, float* __restrict__ out)
{
    int f = *flag;
    size_t i = (size_t)blockIdx.x * 256 + threadIdx.x;
    out[i] = ldin(in, i, f);
}
__global__ __launch_bounds__(256)
void add_k(float* __restrict__ x, const bf16* __restrict__ t)
{
    size_t i = (size_t)blockIdx.x * 256 + threadIdx.x;
    x[i] += bf2f(t[i]);
}
__global__ __launch_bounds__(256)
void silu_k(bf16* __restrict__ u)
{
    size_t i = (size_t)blockIdx.x * 256 + threadIdx.x;
    size_t r = i >> 11;
    int c = (int)(i & 2047);
    float a = bf2f(u[r * 4096 + c]);
    float gg = bf2f(u[r * 4096 + 2048 + c]);
    u[r * 4096 + c] = f2bf(a * (gg / (1.f + expf(-gg))));
}

// ---------------- rel-pos bias table ----------------------------------------
__global__ __launch_bounds__(256)
void bias_k(const void* __restrict__ rpe, const int* __restrict__ flag, float* __restrict__ tab)
{
    int f = *flag;
    int idx = blockIdx.x * 256 + threadIdx.x;
    if (idx >= 8 * 1025) return;
    int h = idx / 1025, dist = idx % 1025;
    int bkt;
    if (dist < 16) bkt = dist;
    else {
        bkt = 16 + (int)(logf((float)dist / 16.f) / logf(8.f) * 16.f);
        if (bkt > 31) bkt = 31;
    }
    tab[idx] = ldin(rpe, bkt * 8 + h, f);
}

// ---------------- q prep -----------------------------------------------------
__global__ __launch_bounds__(256)
void qprep_k(const bf16* __restrict__ qb, bf16* __restrict__ Q)
{
    int rid = blockIdx.x * 4 + (threadIdx.x >> 6);
    int lane = threadIdx.x & 63;
    int h = rid & 7;
    int n = (rid >> 3) & 1023;
    int b = rid >> 13;
    float v = bf2f(qb[(size_t)((b << 10) | n) * 512 + h * 64 + lane]) * 16.f;
    if (lane < 32) {
        int p = lane >> 1;
        float ang = (float)n * expf((float)p * -0.5756462732f);
        float c = cosf(ang), s = sinf(ang);
        float other = __shfl_xor(v, 1, 64);
        float rot = (lane & 1) ? other : -other;
        v = v * c + rot * s;
    }
    float nrm = sqrtf(wave_sum(v * v));
    v = v / fmaxf(nrm, 1e-12f) * 4.f;
    Q[(((size_t)(b * 8 + h)) * 1024 + n) * 64 + lane] = f2bf(v);
}

// ---------------- k/v prep ---------------------------------------------------
__global__ __launch_bounds__(256)
void kvprep_k(const bf16* __restrict__ kvb, const void* __restrict__ nkv, int nkoff,
              const int* __restrict__ flag, bf16* __restrict__ K, bf16* __restrict__ V)
{
    int f = *flag;
    int rid = blockIdx.x * 4 + (threadIdx.x >> 6);
    if (rid >= 4 * 1025) return;
    int lane = threadIdx.x & 63;
    int j = rid % 1025;
    int b = rid / 1025;
    float kv, vv;
    if (j == 0) {
        kv = ldin(nkv, nkoff + lane, f);
        vv = ldin(nkv, nkoff + 64 + lane, f);
    } else {
        int n = j - 1;
        const bf16* src = kvb + (size_t)(b * 1024 + n) * 128;
        kv = bf2f(src[lane]);
        vv = bf2f(src[64 + lane]);
        if (lane < 32) {
            int p = lane >> 1;
            float ang = (float)n * expf((float)p * -0.5756462732f);
            float c = cosf(ang), s = sinf(ang);
            float other = __shfl_xor(kv, 1, 64);
            float rot = (lane & 1) ? other : -other;
            kv = kv * c + rot * s;
        }
    }
    float nrm = sqrtf(wave_sum(kv * kv));
    kv = kv / fmaxf(nrm, 1e-12f) * 4.f;
    size_t o = ((size_t)b * 1025 + j) * 64 + lane;
    K[o] = f2bf(kv);
    V[o] = f2bf(vv);
}

// ---------------- attention: online softmax, wave per query row --------------
__global__ __launch_bounds__(256)
void attn_k(const bf16* __restrict__ Q, const bf16* __restrict__ Kg,
            const bf16* __restrict__ Vg, const float* __restrict__ bias,
            bf16* __restrict__ O)
{
    __shared__ bf16 Ks[64 * 68];
    __shared__ bf16 Vs[64 * 68];
    __shared__ float qs[4][64];
    __shared__ float ps[4][64];
    int bh = blockIdx.x;
    int b = bh >> 3, h = bh & 7;
    int t = threadIdx.x, lane = t & 63, w = t >> 6;
    int i = blockIdx.y * 4 + w;
    qs[w][lane] = bf2f(Q[((size_t)bh * 1024 + i) * 64 + lane]);
    const float* bt = bias + h * 1025;
    const bf16* Kb = Kg + (size_t)b * 1025 * 64;
    const bf16* Vb = Vg + (size_t)b * 1025 * 64;
    float m_run = -3e38f, l_run = 0.f, o = 0.f;
    int jmax = blockIdx.y * 4 + 4;
    int nch = (jmax >> 6) + 1;
    for (int ch = 0; ch < nch; ++ch) {
        __syncthreads();
        int j0 = ch * 64;
#pragma unroll
        for (int r = 0; r < 2; ++r) {
            int c = t + 256 * r;
            int rr = c >> 3;
            int coff = (c & 7) * 8;
            int j = j0 + rr;
            unsigned long long k0v = 0, k1v = 0, v0v = 0, v1v = 0;
            if (j < 1025) {
                ulonglong2 kk = *(const ulonglong2*)(Kb + (size_t)j * 64 + coff);
                ulonglong2 vv = *(const ulonglong2*)(Vb + (size_t)j * 64 + coff);
                k0v = kk.x; k1v = kk.y; v0v = vv.x; v1v = vv.y;
            }
            *(unsigned long long*)(&Ks[rr * 68 + coff])     = k0v;
            *(unsigned long long*)(&Ks[rr * 68 + coff + 4]) = k1v;
            *(unsigned long long*)(&Vs[rr * 68 + coff])     = v0v;
            *(unsigned long long*)(&Vs[rr * 68 + coff + 4]) = v1v;
        }
        __syncthreads();
        int j = j0 + lane;
        float s = -1e30f;
        if (j <= i + 1 && j < 1025) {
            float a = 0.f;
#pragma unroll
            for (int d = 0; d < 64; ++d)
                a += qs[w][d] * bf2f(Ks[lane * 68 + d]);
            int dist = i - j; if (dist < 0) dist = 0;
            s = a + bt[dist];
        }
        float mc = wave_max(s);
        float mnew = fmaxf(m_run, mc);
        float p = expf(s - mnew);
        float lsum = wave_sum(p);
        float alpha = expf(m_run - mnew);
        l_run = l_run * alpha + lsum;
        m_run = mnew;
        ps[w][lane] = p;
        __syncthreads();
        float acc = 0.f;
#pragma unroll
        for (int jj = 0; jj < 64; ++jj)
            acc += ps[w][jj] * bf2f(Vs[jj * 68 + lane]);
        o = o * alpha + acc;
    }
    O[((size_t)(b * 1024 + i) * 512) + h * 64 + lane] = f2bf(o / l_run);
}

// =============================================================================
extern "C" void kernel_launch(void* const* d_in, const int* in_sizes, int n_in,
                              void* d_out, int out_size, void* d_ws, size_t ws_size,
                              hipStream_t stream)
{
    const void* x_in     = d_in[0];
    const void* rpe      = d_in[1];
    const void* g_attn   = d_in[2];
    const void* null_kv  = d_in[3];
    const void* Wq       = d_in[4];
    const void* Wkv      = d_in[5];
    const void* Wo       = d_in[6];
    const void* g_attn_o = d_in[7];
    const void* g_ff     = d_in[8];
    const void* W1       = d_in[9];
    const void* W2       = d_in[10];
    const void* g_final  = d_in[11];
    const void* W_proj   = d_in[12];

    char* wp = (char*)d_ws;
    auto alloc = [&](size_t bytes) {
        char* p = wp; wp += (bytes + 255) & ~(size_t)255; return p;
    };
    float* xf   = (float*)alloc(4096ull * 512 * 4);
    bf16*  xn   = (bf16*) alloc(4096ull * 512 * 2);
    bf16*  tb   = (bf16*) alloc(4096ull * 512 * 2);
    bf16*  ub   = (bf16*) alloc(4096ull * 4096 * 2);
    bf16*  Kb   = (bf16*) alloc(4ull * 1025 * 64 * 2);
    bf16*  Vb   = (bf16*) alloc(4ull * 1025 * 64 * 2);
    float* btab = (float*)alloc(8ull * 1025 * 4);
    int*   dfl  = (int*)  alloc(256);
    bf16*  WqT  = (bf16*) alloc(6ull * 512 * 512 * 2);
    bf16*  WkvT = (bf16*) alloc(6ull * 128 * 512 * 2);
    bf16*  WoT  = (bf16*) alloc(6ull * 512 * 512 * 2);
    bf16*  W1T  = (bf16*) alloc(6ull * 4096 * 512 * 2);
    bf16*  W2T  = (bf16*) alloc(6ull * 512 * 2048 * 2);
    bf16*  WpT  = (bf16*) alloc(512ull * 512 * 2);
    // aliased into ub (lifetimes end before W1 gemm writes ub)
    bf16*  qb   = ub;
    bf16*  Qb   = ub + 2097152;
    bf16*  kvb  = ub + 4194304;
    bf16*  ob   = ub + 4718592;

    detect_k<<<1, 256, 0, stream>>>((const unsigned short*)x_in, dfl);
    transpose_k<<<dim3(16, 16, 6),  dim3(32, 8), 0, stream>>>(Wq, WqT, 512, 512, dfl);
    transpose_k<<<dim3(4, 16, 6),   dim3(32, 8), 0, stream>>>(Wkv, WkvT, 512, 128, dfl);
    transpose_k<<<dim3(16, 16, 6),  dim3(32, 8), 0, stream>>>(Wo, WoT, 512, 512, dfl);
    transpose_k<<<dim3(128, 16, 6), dim3(32, 8), 0, stream>>>(W1, W1T, 512, 4096, dfl);
    transpose_k<<<dim3(16, 64, 6),  dim3(32, 8), 0, stream>>>(W2, W2T, 2048, 512, dfl);
    transpose_k<<<dim3(16, 16, 1),  dim3(32, 8), 0, stream>>>(W_proj, WpT, 512, 512, dfl);
    bias_k<<<33, 256, 0, stream>>>(rpe, dfl, btab);
    x_init<<<8192, 256, 0, stream>>>(x_in, dfl, xf);

    for (int l = 0; l < 6; ++l) {
        ln_k<<<4096, 256, 0, stream>>>(xf, g_attn, l * 512, dfl, xn);
        gemm_bt<<<dim3(32, 4), 256, 0, stream>>>(xn, WqT + (size_t)l * 512 * 512, qb, 4096, 512, 512, 512);
        gemm_bt<<<dim3(32, 1), 256, 0, stream>>>(xn, WkvT + (size_t)l * 128 * 512, kvb, 4096, 128, 512, 512);
        qprep_k<<<8192, 256, 0, stream>>>(qb, Qb);
        kvprep_k<<<1025, 256, 0, stream>>>(kvb, null_kv, l * 128, dfl, Kb, Vb);
        attn_k<<<dim3(32, 256), 256, 0, stream>>>(Qb, Kb, Vb, btab, ob);
        gemm_bt<<<dim3(32, 4), 256, 0, stream>>>(ob, WoT + (size_t)l * 512 * 512, tb, 4096, 512, 512, 512);
        addln_k<<<4096, 256, 0, stream>>>(tb, g_attn_o, l * 512, dfl, xf);
        ln_k<<<4096, 256, 0, stream>>>(xf, g_ff, l * 512, dfl, xn);
        gemm_bt<<<dim3(32, 32), 256, 0, stream>>>(xn, W1T + (size_t)l * 4096 * 512, ub, 4096, 4096, 512, 512);
        silu_k<<<32768, 256, 0, stream>>>(ub);
        gemm_bt<<<dim3(32, 4), 256, 0, stream>>>(ub, W2T + (size_t)l * 512 * 2048, tb, 4096, 512, 2048, 4096);
        add_k<<<8192, 256, 0, stream>>>(xf, tb);
    }
    finln_k<<<4096, 256, 0, stream>>>(xf, g_final, dfl, xn);
    gemm_bt_out<<<dim3(32, 4), 256, 0, stream>>>(xn, WpT, d_out, 4096, 512, 512, 512, dfl);
}

// Round 4
// 1652.317 us; speedup vs baseline: 1.5779x; 1.5779x over previous
//
#include <hip/hip_runtime.h>
#include <hip/hip_bf16.h>
#include <cmath>

using bf16 = __hip_bfloat16;
typedef __bf16 v8bf __attribute__((ext_vector_type(8)));
typedef float  v4f  __attribute__((ext_vector_type(4)));

__device__ __forceinline__ float bf2f(bf16 x) { return __bfloat162float(x); }
__device__ __forceinline__ bf16  f2bf(float x) { return __float2bfloat16(x); }

// flag-aware input load: isf32 ? fp32 : bf16 (element index i from base p)
__device__ __forceinline__ float ldin(const void* p, size_t i, int isf32) {
    if (isf32) return ((const float*)p)[i];
    return bf2f(((const bf16*)p)[i]);
}

__device__ __forceinline__ float wave_sum(float v) {
#pragma unroll
    for (int o = 32; o > 0; o >>= 1) v += __shfl_xor(v, o, 64);
    return v;
}
__device__ __forceinline__ float wave_max(float v) {
#pragma unroll
    for (int o = 32; o > 0; o >>= 1) v = fmaxf(v, __shfl_xor(v, o, 64));
    return v;
}
__device__ __forceinline__ float block_sum(float v, float* sm) {
    v = wave_sum(v);
    int lane = threadIdx.x & 63, w = threadIdx.x >> 6;
    __syncthreads();
    if (lane == 0) sm[w] = v;
    __syncthreads();
    return (sm[0] + sm[1]) + (sm[2] + sm[3]);
}
__device__ __forceinline__ float block_max(float v, float* sm) {
    v = wave_max(v);
    int lane = threadIdx.x & 63, w = threadIdx.x >> 6;
    __syncthreads();
    if (lane == 0) sm[w] = v;
    __syncthreads();
    return fmaxf(fmaxf(sm[0], sm[1]), fmaxf(sm[2], sm[3]));
}

// ---------------- dtype detector -------------------------------------------
__global__ void detect_k(const unsigned short* __restrict__ x, int* __restrict__ flag)
{
    __shared__ int s;
    int t = threadIdx.x;
    if (t == 0) s = 0;
    __syncthreads();
    int bad = 0;
    for (int i = t; i < 4096; i += 256) {
        int e = (x[i] >> 7) & 0xFF;
        if (e >= 147) bad++;
    }
    atomicAdd(&s, bad);
    __syncthreads();
    if (t == 0) *flag = (s > 64) ? 1 : 0;
}

// ---------------- MFMA GEMM: C[M,N] = A[M,K] @ BT[N,K]^T, bf16 in, bf16 out --
__global__ __launch_bounds__(256)
void gemm_bt(const bf16* __restrict__ A, const bf16* __restrict__ BT,
             bf16* __restrict__ C, int M, int N, int K, int lda)
{
    __shared__ bf16 As[128 * 32];
    __shared__ bf16 Bs[128 * 32];
    const int t = threadIdx.x;
    const int lane = t & 63;
    const int wave = t >> 6;
    const int wm = (wave >> 1) * 64;
    const int wn = (wave & 1) * 64;
    const int bm = blockIdx.x * 128;
    const int bn = blockIdx.y * 128;
    const int fr = lane & 15;
    const int fk = (lane >> 4) * 8;

    v4f acc[4][4];
#pragma unroll
    for (int i = 0; i < 4; ++i)
#pragma unroll
        for (int j = 0; j < 4; ++j) { v4f z = {0.f, 0.f, 0.f, 0.f}; acc[i][j] = z; }

    for (int k0 = 0; k0 < K; k0 += 32) {
#pragma unroll
        for (int r = 0; r < 2; ++r) {
            int c = t + 256 * r;
            int row = c >> 2;
            int koff = (c & 3) * 8;
            *(int4*)(&As[row * 32 + koff]) =
                *(const int4*)(A + (size_t)(bm + row) * lda + k0 + koff);
            *(int4*)(&Bs[row * 32 + koff]) =
                *(const int4*)(BT + (size_t)(bn + row) * K + k0 + koff);
        }
        __syncthreads();
        v8bf af[4], bfr[4];
#pragma unroll
        for (int mt = 0; mt < 4; ++mt)
            af[mt] = *(const v8bf*)(&As[(wm + mt * 16 + fr) * 32 + fk]);
#pragma unroll
        for (int nt = 0; nt < 4; ++nt)
            bfr[nt] = *(const v8bf*)(&Bs[(wn + nt * 16 + fr) * 32 + fk]);
#pragma unroll
        for (int mt = 0; mt < 4; ++mt)
#pragma unroll
            for (int nt = 0; nt < 4; ++nt)
                acc[mt][nt] = __builtin_amdgcn_mfma_f32_16x16x32_bf16(
                    af[mt], bfr[nt], acc[mt][nt], 0, 0, 0);
        __syncthreads();
    }
    const int r0 = (lane >> 4) * 4;
#pragma unroll
    for (int mt = 0; mt < 4; ++mt)
#pragma unroll
        for (int nt = 0; nt < 4; ++nt)
#pragma unroll
            for (int r = 0; r < 4; ++r) {
                int row = bm + wm + mt * 16 + r0 + r;
                int col = bn + wn + nt * 16 + fr;
                C[(size_t)row * N + col] = f2bf(acc[mt][nt][r]);
            }
}

// ---- same GEMM but output dtype chosen by flag: f32 when flag=1, else bf16 --
__global__ __launch_bounds__(256)
void gemm_bt_out(const bf16* __restrict__ A, const bf16* __restrict__ BT,
                 void* __restrict__ C, int M, int N, int K, int lda,
                 const int* __restrict__ flag)
{
    __shared__ bf16 As[128 * 32];
    __shared__ bf16 Bs[128 * 32];
    const int f = *flag;
    const int t = threadIdx.x;
    const int lane = t & 63;
    const int wave = t >> 6;
    const int wm = (wave >> 1) * 64;
    const int wn = (wave & 1) * 64;
    const int bm = blockIdx.x * 128;
    const int bn = blockIdx.y * 128;
    const int fr = lane & 15;
    const int fk = (lane >> 4) * 8;

    v4f acc[4][4];
#pragma unroll
    for (int i = 0; i < 4; ++i)
#pragma unroll
        for (int j = 0; j < 4; ++j) { v4f z = {0.f, 0.f, 0.f, 0.f}; acc[i][j] = z; }

    for (int k0 = 0; k0 < K; k0 += 32) {
#pragma unroll
        for (int r = 0; r < 2; ++r) {
            int c = t + 256 * r;
            int row = c >> 2;
            int koff = (c & 3) * 8;
            *(int4*)(&As[row * 32 + koff]) =
                *(const int4*)(A + (size_t)(bm + row) * lda + k0 + koff);
            *(int4*)(&Bs[row * 32 + koff]) =
                *(const int4*)(BT + (size_t)(bn + row) * K + k0 + koff);
        }
        __syncthreads();
        v8bf af[4], bfr[4];
#pragma unroll
        for (int mt = 0; mt < 4; ++mt)
            af[mt] = *(const v8bf*)(&As[(wm + mt * 16 + fr) * 32 + fk]);
#pragma unroll
        for (int nt = 0; nt < 4; ++nt)
            bfr[nt] = *(const v8bf*)(&Bs[(wn + nt * 16 + fr) * 32 + fk]);
#pragma unroll
        for (int mt = 0; mt < 4; ++mt)
#pragma unroll
            for (int nt = 0; nt < 4; ++nt)
                acc[mt][nt] = __builtin_amdgcn_mfma_f32_16x16x32_bf16(
                    af[mt], bfr[nt], acc[mt][nt], 0, 0, 0);
        __syncthreads();
    }
    const int r0 = (lane >> 4) * 4;
#pragma unroll
    for (int mt = 0; mt < 4; ++mt)
#pragma unroll
        for (int nt = 0; nt < 4; ++nt)
#pragma unroll
            for (int r = 0; r < 4; ++r) {
                int row = bm + wm + mt * 16 + r0 + r;
                int col = bn + wn + nt * 16 + fr;
                if (f) ((float*)C)[(size_t)row * N + col] = acc[mt][nt][r];
                else   ((bf16*)C)[(size_t)row * N + col] = f2bf(acc[mt][nt][r]);
            }
}

// ---------------- transpose + dtype-cast: out[z][c][r] = in[z][r][c] ---------
__global__ __launch_bounds__(256)
void transpose_k(const void* __restrict__ in, bf16* __restrict__ out, int R, int C,
                 const int* __restrict__ flag)
{
    __shared__ bf16 tile[32][33];
    int f = *flag;
    size_t zoff = (size_t)blockIdx.z * R * C;
    bf16* dst = out + zoff;
    int c0 = blockIdx.x * 32, r0 = blockIdx.y * 32;
    int tx = threadIdx.x, ty = threadIdx.y;
#pragma unroll
    for (int i = 0; i < 32; i += 8)
        tile[ty + i][tx] = f2bf(ldin(in, zoff + (size_t)(r0 + ty + i) * C + c0 + tx, f));
    __syncthreads();
#pragma unroll
    for (int i = 0; i < 32; i += 8)
        dst[(size_t)(c0 + ty + i) * R + r0 + tx] = tile[tx][ty + i];
}

// ---------------- LayerNorm (D=512), x fp32 -> out bf16 ----------------------
__global__ __launch_bounds__(256)
void ln_k(const float* __restrict__ x, const void* __restrict__ g, int goff,
          const int* __restrict__ flag, bf16* __restrict__ out)
{
    __shared__ float sm[4];
    int f = *flag;
    int row = blockIdx.x, t = threadIdx.x;
    const float* xr = x + (size_t)row * 512;
    float v0 = xr[t], v1 = xr[t + 256];
    float mean = block_sum(v0 + v1, sm) * (1.f / 512.f);
    float d0 = v0 - mean, d1 = v1 - mean;
    float var = block_sum(d0 * d0 + d1 * d1, sm) * (1.f / 512.f);
    float rstd = rsqrtf(var + 1e-5f);
    out[(size_t)row * 512 + t]       = f2bf(d0 * rstd * ldin(g, goff + t, f));
    out[(size_t)row * 512 + t + 256] = f2bf(d1 * rstd * ldin(g, goff + t + 256, f));
}

// ---------------- x += LN(t) -------------------------------------------------
__global__ __launch_bounds__(256)
void addln_k(const bf16* __restrict__ tin, const void* __restrict__ g, int goff,
             const int* __restrict__ flag, float* __restrict__ x)
{
    __shared__ float sm[4];
    int f = *flag;
    int row = blockIdx.x, t = threadIdx.x;
    const bf16* tr = tin + (size_t)row * 512;
    float v0 = bf2f(tr[t]), v1 = bf2f(tr[t + 256]);
    float mean = block_sum(v0 + v1, sm) * (1.f / 512.f);
    float d0 = v0 - mean, d1 = v1 - mean;
    float var = block_sum(d0 * d0 + d1 * d1, sm) * (1.f / 512.f);
    float rstd = rsqrtf(var + 1e-5f);
    x[(size_t)row * 512 + t]       += d0 * rstd * ldin(g, goff + t, f);
    x[(size_t)row * 512 + t + 256] += d1 * rstd * ldin(g, goff + t + 256, f);
}

// ---------------- final stable LN --------------------------------------------
__global__ __launch_bounds__(256)
void finln_k(const float* __restrict__ x, const void* __restrict__ g,
             const int* __restrict__ flag, bf16* __restrict__ out)
{
    __shared__ float sm[4];
    int f = *flag;
    int row = blockIdx.x, t = threadIdx.x;
    const float* xr = x + (size_t)row * 512;
    float v0 = xr[t], v1 = xr[t + 256];
    float mx = block_max(fmaxf(v0, v1), sm);
    v0 /= mx; v1 /= mx;
    float mean = block_sum(v0 + v1, sm) * (1.f / 512.f);
    float d0 = v0 - mean, d1 = v1 - mean;
    float var = block_sum(d0 * d0 + d1 * d1, sm) * (1.f / 512.f);
    float rstd = rsqrtf(var + 1e-5f);
    out[(size_t)row * 512 + t]       = f2bf(d0 * rstd * ldin(g, t, f));
    out[(size_t)row * 512 + t + 256] = f2bf(d1 * rstd * ldin(g, t + 256, f));
}

// ---------------- misc elementwise -------------------------------------------
__global__ __launch_bounds__(256)
void x_init(const void* __restrict__ in, const int* __restrict__ flag, float* __restrict__ out)
{
    int f = *flag;
    size_t i = (size_t)blockIdx.x * 256 + threadIdx.x;
    out[i] = ldin(in, i, f);
}
__global__ __launch_bounds__(256)
void add_k(float* __restrict__ x, const bf16* __restrict__ t)
{
    size_t i = (size_t)blockIdx.x * 256 + threadIdx.x;
    x[i] += bf2f(t[i]);
}
__global__ __launch_bounds__(256)
void silu_k(bf16* __restrict__ u)
{
    size_t i = (size_t)blockIdx.x * 256 + threadIdx.x;
    size_t r = i >> 11;
    int c = (int)(i & 2047);
    float a = bf2f(u[r * 4096 + c]);
    float gg = bf2f(u[r * 4096 + 2048 + c]);
    u[r * 4096 + c] = f2bf(a * (gg / (1.f + expf(-gg))));
}

// ---------------- rel-pos bias table ----------------------------------------
__global__ __launch_bounds__(256)
void bias_k(const void* __restrict__ rpe, const int* __restrict__ flag, float* __restrict__ tab)
{
    int f = *flag;
    int idx = blockIdx.x * 256 + threadIdx.x;
    if (idx >= 8 * 1025) return;
    int h = idx / 1025, dist = idx % 1025;
    int bkt;
    if (dist < 16) bkt = dist;
    else {
        bkt = 16 + (int)(logf((float)dist / 16.f) / logf(8.f) * 16.f);
        if (bkt > 31) bkt = 31;
    }
    tab[idx] = ldin(rpe, bkt * 8 + h, f);
}

// ---------------- q prep -----------------------------------------------------
__global__ __launch_bounds__(256)
void qprep_k(const bf16* __restrict__ qb, bf16* __restrict__ Q)
{
    int rid = blockIdx.x * 4 + (threadIdx.x >> 6);
    int lane = threadIdx.x & 63;
    int h = rid & 7;
    int n = (rid >> 3) & 1023;
    int b = rid >> 13;
    float v = bf2f(qb[(size_t)((b << 10) | n) * 512 + h * 64 + lane]) * 16.f;
    if (lane < 32) {
        int p = lane >> 1;
        float ang = (float)n * expf((float)p * -0.5756462732f);
        float c = cosf(ang), s = sinf(ang);
        float other = __shfl_xor(v, 1, 64);
        float rot = (lane & 1) ? other : -other;
        v = v * c + rot * s;
    }
    float nrm = sqrtf(wave_sum(v * v));
    v = v / fmaxf(nrm, 1e-12f) * 4.f;
    Q[(((size_t)(b * 8 + h)) * 1024 + n) * 64 + lane] = f2bf(v);
}

// ---------------- k/v prep: K[b][j][d] (1088-padded rows), Vt[b][d][j] -------
__global__ __launch_bounds__(256)
void kvprep_k(const bf16* __restrict__ kvb, const void* __restrict__ nkv, int nkoff,
              const int* __restrict__ flag, bf16* __restrict__ K, bf16* __restrict__ Vt)
{
    int f = *flag;
    int rid = blockIdx.x * 4 + (threadIdx.x >> 6);
    if (rid >= 4 * 1025) return;
    int lane = threadIdx.x & 63;
    int j = rid % 1025;
    int b = rid / 1025;
    float kv, vv;
    if (j == 0) {
        kv = ldin(nkv, nkoff + lane, f);
        vv = ldin(nkv, nkoff + 64 + lane, f);
    } else {
        int n = j - 1;
        const bf16* src = kvb + (size_t)(b * 1024 + n) * 128;
        kv = bf2f(src[lane]);
        vv = bf2f(src[64 + lane]);
        if (lane < 32) {
            int p = lane >> 1;
            float ang = (float)n * expf((float)p * -0.5756462732f);
            float c = cosf(ang), s = sinf(ang);
            float other = __shfl_xor(kv, 1, 64);
            float rot = (lane & 1) ? other : -other;
            kv = kv * c + rot * s;
        }
    }
    float nrm = sqrtf(wave_sum(kv * kv));
    kv = kv / fmaxf(nrm, 1e-12f) * 4.f;
    K[((size_t)b * 1088 + j) * 64 + lane] = f2bf(kv);
    Vt[((size_t)b * 64 + lane) * 1088 + j] = f2bf(vv);
}

// ---------------- MFMA flash attention ---------------------------------------
// grid (B*H, N/64), block 256 = 4 waves; wave w handles query rows i0+w*16+0..15
__global__ __launch_bounds__(256)
void attn_mfma(const bf16* __restrict__ Q, const bf16* __restrict__ Kg,
               const bf16* __restrict__ Vtg, const float* __restrict__ bias,
               bf16* __restrict__ O)
{
    __shared__ bf16 Ks[64][72];      // [key][dim]
    __shared__ bf16 Vts[64][72];     // [dim][key]
    __shared__ bf16 Ps[4][16][72];   // per-wave P round-trip (C->A layout)
    const int bh = blockIdx.x, b = bh >> 3, h = bh & 7;
    const int i0 = blockIdx.y * 64;
    const int t = threadIdx.x, lane = t & 63, w = t >> 6;
    const int col = lane & 15;       // n/m index within 16-tile
    const int quad = lane >> 4;      // 0..3
    const int fk = quad * 8;         // k-offset within frag
    const float* bt = bias + h * 1025;
    const bf16* Kb = Kg + (size_t)b * 1088 * 64;
    const bf16* Vb = Vtg + (size_t)b * 64 * 1088;

    // Q A-fragments (k-steps over 64 dims)
    v8bf qf[2];
    const bf16* qrow = Q + ((size_t)bh * 1024 + i0 + w * 16 + col) * 64;
#pragma unroll
    for (int s = 0; s < 2; ++s)
        qf[s] = *(const v8bf*)(qrow + s * 32 + fk);

    v4f oacc[4];
#pragma unroll
    for (int dt = 0; dt < 4; ++dt) { v4f z = {0.f,0.f,0.f,0.f}; oacc[dt] = z; }
    float m_run[4] = {-3e38f, -3e38f, -3e38f, -3e38f};
    float l_run[4] = {0.f, 0.f, 0.f, 0.f};

    const int nch = blockIdx.y + 2;
    for (int ch = 0; ch < nch; ++ch) {
        const int j0 = ch * 64;
        __syncthreads();
#pragma unroll
        for (int rep = 0; rep < 2; ++rep) {
            int c = t + 256 * rep;
            int rr = c >> 3;
            int coff = (c & 7) * 8;
            *(v8bf*)(&Ks[rr][coff])  = *(const v8bf*)(Kb + (size_t)(j0 + rr) * 64 + coff);
            *(v8bf*)(&Vts[rr][coff]) = *(const v8bf*)(Vb + (size_t)rr * 1088 + j0 + coff);
        }
        __syncthreads();
        // S = Q K^T : 4 key-tiles of 16
        v4f sreg[4];
#pragma unroll
        for (int nt = 0; nt < 4; ++nt) {
            v4f z = {0.f,0.f,0.f,0.f};
            v8bf kf0 = *(const v8bf*)(&Ks[nt * 16 + col][fk]);
            v8bf kf1 = *(const v8bf*)(&Ks[nt * 16 + col][32 + fk]);
            z = __builtin_amdgcn_mfma_f32_16x16x32_bf16(qf[0], kf0, z, 0, 0, 0);
            z = __builtin_amdgcn_mfma_f32_16x16x32_bf16(qf[1], kf1, z, 0, 0, 0);
            sreg[nt] = z;
        }
        // bias + causal mask + online softmax (row = i0+w*16+quad*4+reg)
        float p[4][4];
#pragma unroll
        for (int reg = 0; reg < 4; ++reg) {
            int i = i0 + w * 16 + quad * 4 + reg;
            float mx = -3e38f;
#pragma unroll
            for (int nt = 0; nt < 4; ++nt) {
                int j = j0 + nt * 16 + col;
                float s;
                if (j <= i + 1 && j < 1025) {
                    int dist = i - j; if (dist < 0) dist = 0;
                    s = sreg[nt][reg] + bt[dist];
                } else s = -1e30f;
                sreg[nt][reg] = s;
                mx = fmaxf(mx, s);
            }
#pragma unroll
            for (int o = 1; o < 16; o <<= 1) mx = fmaxf(mx, __shfl_xor(mx, o, 64));
            float mnew = fmaxf(m_run[reg], mx);
            float alpha = expf(m_run[reg] - mnew);
            float ls = 0.f;
#pragma unroll
            for (int nt = 0; nt < 4; ++nt) {
                float pp = expf(sreg[nt][reg] - mnew);
                p[nt][reg] = pp;
                ls += pp;
            }
#pragma unroll
            for (int o = 1; o < 16; o <<= 1) ls += __shfl_xor(ls, o, 64);
            l_run[reg] = l_run[reg] * alpha + ls;
            m_run[reg] = mnew;
#pragma unroll
            for (int dt = 0; dt < 4; ++dt) oacc[dt][reg] *= alpha;
        }
        // P: C-layout -> LDS -> A-layout (wave-private region, no barrier)
#pragma unroll
        for (int reg = 0; reg < 4; ++reg) {
            int row = quad * 4 + reg;
#pragma unroll
            for (int nt = 0; nt < 4; ++nt)
                Ps[w][row][nt * 16 + col] = f2bf(p[nt][reg]);
        }
        v8bf pf[2];
#pragma unroll
        for (int ks = 0; ks < 2; ++ks)
            pf[ks] = *(const v8bf*)(&Ps[w][col][ks * 32 + fk]);
        // O += P @ V  (V via Vt: B-frag rows are contiguous keys)
#pragma unroll
        for (int dt = 0; dt < 4; ++dt) {
#pragma unroll
            for (int ks = 0; ks < 2; ++ks) {
                v8bf vf = *(const v8bf*)(&Vts[dt * 16 + col][ks * 32 + fk]);
                oacc[dt] = __builtin_amdgcn_mfma_f32_16x16x32_bf16(pf[ks], vf, oacc[dt], 0, 0, 0);
            }
        }
    }
    // epilogue: O[b, i, h*64 + d]
#pragma unroll
    for (int reg = 0; reg < 4; ++reg) {
        int i = i0 + w * 16 + quad * 4 + reg;
        float inv = 1.f / l_run[reg];
#pragma unroll
        for (int dt = 0; dt < 4; ++dt)
            O[((size_t)(b * 1024 + i)) * 512 + h * 64 + dt * 16 + col] =
                f2bf(oacc[dt][reg] * inv);
    }
}

// =============================================================================
extern "C" void kernel_launch(void* const* d_in, const int* in_sizes, int n_in,
                              void* d_out, int out_size, void* d_ws, size_t ws_size,
                              hipStream_t stream)
{
    const void* x_in     = d_in[0];
    const void* rpe      = d_in[1];
    const void* g_attn   = d_in[2];
    const void* null_kv  = d_in[3];
    const void* Wq       = d_in[4];
    const void* Wkv      = d_in[5];
    const void* Wo       = d_in[6];
    const void* g_attn_o = d_in[7];
    const void* g_ff     = d_in[8];
    const void* W1       = d_in[9];
    const void* W2       = d_in[10];
    const void* g_final  = d_in[11];
    const void* W_proj   = d_in[12];

    char* wp = (char*)d_ws;
    auto alloc = [&](size_t bytes) {
        char* p = wp; wp += (bytes + 255) & ~(size_t)255; return p;
    };
    float* xf   = (float*)alloc(4096ull * 512 * 4);
    bf16*  xn   = (bf16*) alloc(4096ull * 512 * 2);
    bf16*  tb   = (bf16*) alloc(4096ull * 512 * 2);
    bf16*  ub   = (bf16*) alloc(4096ull * 4096 * 2);
    bf16*  Kb   = (bf16*) alloc(4ull * 1088 * 64 * 2);
    bf16*  Vtb  = (bf16*) alloc(4ull * 64 * 1088 * 2);
    float* btab = (float*)alloc(8ull * 1025 * 4);
    int*   dfl  = (int*)  alloc(256);
    bf16*  WqT  = (bf16*) alloc(6ull * 512 * 512 * 2);
    bf16*  WkvT = (bf16*) alloc(6ull * 128 * 512 * 2);
    bf16*  WoT  = (bf16*) alloc(6ull * 512 * 512 * 2);
    bf16*  W1T  = (bf16*) alloc(6ull * 4096 * 512 * 2);
    bf16*  W2T  = (bf16*) alloc(6ull * 512 * 2048 * 2);
    bf16*  WpT  = (bf16*) alloc(512ull * 512 * 2);
    // aliased into ub (lifetimes end before W1 gemm writes ub)
    bf16*  qb   = ub;
    bf16*  Qb   = ub + 2097152;
    bf16*  kvb  = ub + 4194304;
    bf16*  ob   = ub + 4718592;

    detect_k<<<1, 256, 0, stream>>>((const unsigned short*)x_in, dfl);
    transpose_k<<<dim3(16, 16, 6),  dim3(32, 8), 0, stream>>>(Wq, WqT, 512, 512, dfl);
    transpose_k<<<dim3(4, 16, 6),   dim3(32, 8), 0, stream>>>(Wkv, WkvT, 512, 128, dfl);
    transpose_k<<<dim3(16, 16, 6),  dim3(32, 8), 0, stream>>>(Wo, WoT, 512, 512, dfl);
    transpose_k<<<dim3(128, 16, 6), dim3(32, 8), 0, stream>>>(W1, W1T, 512, 4096, dfl);
    transpose_k<<<dim3(16, 64, 6),  dim3(32, 8), 0, stream>>>(W2, W2T, 2048, 512, dfl);
    transpose_k<<<dim3(16, 16, 1),  dim3(32, 8), 0, stream>>>(W_proj, WpT, 512, 512, dfl);
    bias_k<<<33, 256, 0, stream>>>(rpe, dfl, btab);
    x_init<<<8192, 256, 0, stream>>>(x_in, dfl, xf);

    for (int l = 0; l < 6; ++l) {
        ln_k<<<4096, 256, 0, stream>>>(xf, g_attn, l * 512, dfl, xn);
        gemm_bt<<<dim3(32, 4), 256, 0, stream>>>(xn, WqT + (size_t)l * 512 * 512, qb, 4096, 512, 512, 512);
        gemm_bt<<<dim3(32, 1), 256, 0, stream>>>(xn, WkvT + (size_t)l * 128 * 512, kvb, 4096, 128, 512, 512);
        qprep_k<<<8192, 256, 0, stream>>>(qb, Qb);
        kvprep_k<<<1025, 256, 0, stream>>>(kvb, null_kv, l * 128, dfl, Kb, Vtb);
        attn_mfma<<<dim3(32, 16), 256, 0, stream>>>(Qb, Kb, Vtb, btab, ob);
        gemm_bt<<<dim3(32, 4), 256, 0, stream>>>(ob, WoT + (size_t)l * 512 * 512, tb, 4096, 512, 512, 512);
        addln_k<<<4096, 256, 0, stream>>>(tb, g_attn_o, l * 512, dfl, xf);
        ln_k<<<4096, 256, 0, stream>>>(xf, g_ff, l * 512, dfl, xn);
        gemm_bt<<<dim3(32, 32), 256, 0, stream>>>(xn, W1T + (size_t)l * 4096 * 512, ub, 4096, 4096, 512, 512);
        silu_k<<<32768, 256, 0, stream>>>(ub);
        gemm_bt<<<dim3(32, 4), 256, 0, stream>>>(ub, W2T + (size_t)l * 512 * 2048, tb, 4096, 512, 2048, 4096);
        add_k<<<8192, 256, 0, stream>>>(xf, tb);
    }
    finln_k<<<4096, 256, 0, stream>>>(xf, g_final, dfl, xn);
    gemm_bt_out<<<dim3(32, 4), 256, 0, stream>>>(xn, WpT, d_out, 4096, 512, 512, 512, dfl);
}

// Round 6
// 1452.883 us; speedup vs baseline: 1.7945x; 1.1373x over previous
//
#include <hip/hip_runtime.h>
#include <hip/hip_bf16.h>
#include <cmath>

using bf16 = __hip_bfloat16;
typedef __bf16 v8bf __attribute__((ext_vector_type(8)));
typedef float  v4f  __attribute__((ext_vector_type(4)));

__device__ __forceinline__ float bf2f(bf16 x) { return __bfloat162float(x); }
__device__ __forceinline__ bf16  f2bf(float x) { return __float2bfloat16(x); }

__device__ __forceinline__ float ldin(const void* p, size_t i, int isf32) {
    if (isf32) return ((const float*)p)[i];
    return bf2f(((const bf16*)p)[i]);
}

__device__ __forceinline__ float wave_sum(float v) {
#pragma unroll
    for (int o = 32; o > 0; o >>= 1) v += __shfl_xor(v, o, 64);
    return v;
}
__device__ __forceinline__ float wave_max(float v) {
#pragma unroll
    for (int o = 32; o > 0; o >>= 1) v = fmaxf(v, __shfl_xor(v, o, 64));
    return v;
}
__device__ __forceinline__ float block_sum(float v, float* sm) {
    v = wave_sum(v);
    int lane = threadIdx.x & 63, w = threadIdx.x >> 6;
    __syncthreads();
    if (lane == 0) sm[w] = v;
    __syncthreads();
    return (sm[0] + sm[1]) + (sm[2] + sm[3]);
}
__device__ __forceinline__ float block_max(float v, float* sm) {
    v = wave_max(v);
    int lane = threadIdx.x & 63, w = threadIdx.x >> 6;
    __syncthreads();
    if (lane == 0) sm[w] = v;
    __syncthreads();
    return fmaxf(fmaxf(sm[0], sm[1]), fmaxf(sm[2], sm[3]));
}

// ---------------- dtype detector -------------------------------------------
__global__ void detect_k(const unsigned short* __restrict__ x, int* __restrict__ flag)
{
    __shared__ int s;
    int t = threadIdx.x;
    if (t == 0) s = 0;
    __syncthreads();
    int bad = 0;
    for (int i = t; i < 4096; i += 256) {
        int e = (x[i] >> 7) & 0xFF;
        if (e >= 147) bad++;
    }
    atomicAdd(&s, bad);
    __syncthreads();
    if (t == 0) *flag = (s > 64) ? 1 : 0;
}

// ---------------- MFMA GEMM 128x128: C[M,N] = A[M,K] @ BT[N,K]^T -------------
__global__ __launch_bounds__(256)
void gemm_bt(const bf16* __restrict__ A, const bf16* __restrict__ BT,
             bf16* __restrict__ C, int M, int N, int K, int lda)
{
    __shared__ bf16 As[128 * 32];
    __shared__ bf16 Bs[128 * 32];
    const int t = threadIdx.x;
    const int lane = t & 63;
    const int wave = t >> 6;
    const int wm = (wave >> 1) * 64;
    const int wn = (wave & 1) * 64;
    const int bm = blockIdx.x * 128;
    const int bn = blockIdx.y * 128;
    const int fr = lane & 15;
    const int fk = (lane >> 4) * 8;

    v4f acc[4][4];
#pragma unroll
    for (int i = 0; i < 4; ++i)
#pragma unroll
        for (int j = 0; j < 4; ++j) { v4f z = {0.f, 0.f, 0.f, 0.f}; acc[i][j] = z; }

    for (int k0 = 0; k0 < K; k0 += 32) {
#pragma unroll
        for (int r = 0; r < 2; ++r) {
            int c = t + 256 * r;
            int row = c >> 2;
            int koff = (c & 3) * 8;
            *(int4*)(&As[row * 32 + koff]) =
                *(const int4*)(A + (size_t)(bm + row) * lda + k0 + koff);
            *(int4*)(&Bs[row * 32 + koff]) =
                *(const int4*)(BT + (size_t)(bn + row) * K + k0 + koff);
        }
        __syncthreads();
        v8bf af[4], bfr[4];
#pragma unroll
        for (int mt = 0; mt < 4; ++mt)
            af[mt] = *(const v8bf*)(&As[(wm + mt * 16 + fr) * 32 + fk]);
#pragma unroll
        for (int nt = 0; nt < 4; ++nt)
            bfr[nt] = *(const v8bf*)(&Bs[(wn + nt * 16 + fr) * 32 + fk]);
#pragma unroll
        for (int mt = 0; mt < 4; ++mt)
#pragma unroll
            for (int nt = 0; nt < 4; ++nt)
                acc[mt][nt] = __builtin_amdgcn_mfma_f32_16x16x32_bf16(
                    af[mt], bfr[nt], acc[mt][nt], 0, 0, 0);
        __syncthreads();
    }
    const int r0 = (lane >> 4) * 4;
#pragma unroll
    for (int mt = 0; mt < 4; ++mt)
#pragma unroll
        for (int nt = 0; nt < 4; ++nt)
#pragma unroll
            for (int r = 0; r < 4; ++r) {
                int row = bm + wm + mt * 16 + r0 + r;
                int col = bn + wn + nt * 16 + fr;
                C[(size_t)row * N + col] = f2bf(acc[mt][nt][r]);
            }
}

// ---------------- MFMA GEMM 64x128 tile (for skinny-N GEMMs, more blocks) ----
__global__ __launch_bounds__(256)
void gemm64(const bf16* __restrict__ A, const bf16* __restrict__ BT,
            bf16* __restrict__ C, int M, int N, int K, int lda)
{
    __shared__ bf16 As[64 * 32];
    __shared__ bf16 Bs[128 * 32];
    const int t = threadIdx.x;
    const int lane = t & 63;
    const int wave = t >> 6;
    const int wm = (wave >> 1) * 32;
    const int wn = (wave & 1) * 64;
    const int bm = blockIdx.x * 64;
    const int bn = blockIdx.y * 128;
    const int fr = lane & 15;
    const int fk = (lane >> 4) * 8;

    v4f acc[2][4];
#pragma unroll
    for (int i = 0; i < 2; ++i)
#pragma unroll
        for (int j = 0; j < 4; ++j) { v4f z = {0.f, 0.f, 0.f, 0.f}; acc[i][j] = z; }

    for (int k0 = 0; k0 < K; k0 += 32) {
        {
            int c = t;
            int row = c >> 2, koff = (c & 3) * 8;
            *(int4*)(&As[row * 32 + koff]) =
                *(const int4*)(A + (size_t)(bm + row) * lda + k0 + koff);
        }
#pragma unroll
        for (int r = 0; r < 2; ++r) {
            int c = t + 256 * r;
            int row = c >> 2, koff = (c & 3) * 8;
            *(int4*)(&Bs[row * 32 + koff]) =
                *(const int4*)(BT + (size_t)(bn + row) * K + k0 + koff);
        }
        __syncthreads();
        v8bf af[2], bfr[4];
#pragma unroll
        for (int mt = 0; mt < 2; ++mt)
            af[mt] = *(const v8bf*)(&As[(wm + mt * 16 + fr) * 32 + fk]);
#pragma unroll
        for (int nt = 0; nt < 4; ++nt)
            bfr[nt] = *(const v8bf*)(&Bs[(wn + nt * 16 + fr) * 32 + fk]);
#pragma unroll
        for (int mt = 0; mt < 2; ++mt)
#pragma unroll
            for (int nt = 0; nt < 4; ++nt)
                acc[mt][nt] = __builtin_amdgcn_mfma_f32_16x16x32_bf16(
                    af[mt], bfr[nt], acc[mt][nt], 0, 0, 0);
        __syncthreads();
    }
    const int r0 = (lane >> 4) * 4;
#pragma unroll
    for (int mt = 0; mt < 2; ++mt)
#pragma unroll
        for (int nt = 0; nt < 4; ++nt)
#pragma unroll
            for (int r = 0; r < 4; ++r) {
                int row = bm + wm + mt * 16 + r0 + r;
                int col = bn + wn + nt * 16 + fr;
                C[(size_t)row * N + col] = f2bf(acc[mt][nt][r]);
            }
}

// ---- gemm64 with flag-selected output dtype (final projection) --------------
__global__ __launch_bounds__(256)
void gemm64_out(const bf16* __restrict__ A, const bf16* __restrict__ BT,
                void* __restrict__ C, int M, int N, int K, int lda,
                const int* __restrict__ flag)
{
    __shared__ bf16 As[64 * 32];
    __shared__ bf16 Bs[128 * 32];
    const int f = *flag;
    const int t = threadIdx.x;
    const int lane = t & 63;
    const int wave = t >> 6;
    const int wm = (wave >> 1) * 32;
    const int wn = (wave & 1) * 64;
    const int bm = blockIdx.x * 64;
    const int bn = blockIdx.y * 128;
    const int fr = lane & 15;
    const int fk = (lane >> 4) * 8;

    v4f acc[2][4];
#pragma unroll
    for (int i = 0; i < 2; ++i)
#pragma unroll
        for (int j = 0; j < 4; ++j) { v4f z = {0.f, 0.f, 0.f, 0.f}; acc[i][j] = z; }

    for (int k0 = 0; k0 < K; k0 += 32) {
        {
            int c = t;
            int row = c >> 2, koff = (c & 3) * 8;
            *(int4*)(&As[row * 32 + koff]) =
                *(const int4*)(A + (size_t)(bm + row) * lda + k0 + koff);
        }
#pragma unroll
        for (int r = 0; r < 2; ++r) {
            int c = t + 256 * r;
            int row = c >> 2, koff = (c & 3) * 8;
            *(int4*)(&Bs[row * 32 + koff]) =
                *(const int4*)(BT + (size_t)(bn + row) * K + k0 + koff);
        }
        __syncthreads();
        v8bf af[2], bfr[4];
#pragma unroll
        for (int mt = 0; mt < 2; ++mt)
            af[mt] = *(const v8bf*)(&As[(wm + mt * 16 + fr) * 32 + fk]);
#pragma unroll
        for (int nt = 0; nt < 4; ++nt)
            bfr[nt] = *(const v8bf*)(&Bs[(wn + nt * 16 + fr) * 32 + fk]);
#pragma unroll
        for (int mt = 0; mt < 2; ++mt)
#pragma unroll
            for (int nt = 0; nt < 4; ++nt)
                acc[mt][nt] = __builtin_amdgcn_mfma_f32_16x16x32_bf16(
                    af[mt], bfr[nt], acc[mt][nt], 0, 0, 0);
        __syncthreads();
    }
    const int r0 = (lane >> 4) * 4;
#pragma unroll
    for (int mt = 0; mt < 2; ++mt)
#pragma unroll
        for (int nt = 0; nt < 4; ++nt)
#pragma unroll
            for (int r = 0; r < 4; ++r) {
                int row = bm + wm + mt * 16 + r0 + r;
                int col = bn + wn + nt * 16 + fr;
                if (f) ((float*)C)[(size_t)row * N + col] = acc[mt][nt][r];
                else   ((bf16*)C)[(size_t)row * N + col] = f2bf(acc[mt][nt][r]);
            }
}

// ---------------- transpose w/ separate z-strides ----------------------------
__global__ __launch_bounds__(256)
void transpose2_k(const void* __restrict__ in, bf16* __restrict__ out, int R, int C,
                  size_t inZ, size_t outZ, const int* __restrict__ flag)
{
    __shared__ bf16 tile[32][33];
    int f = *flag;
    size_t ioff = (size_t)blockIdx.z * inZ;
    bf16* dst = out + (size_t)blockIdx.z * outZ;
    int c0 = blockIdx.x * 32, r0 = blockIdx.y * 32;
    int tx = threadIdx.x, ty = threadIdx.y;
#pragma unroll
    for (int i = 0; i < 32; i += 8)
        tile[ty + i][tx] = f2bf(ldin(in, ioff + (size_t)(r0 + ty + i) * C + c0 + tx, f));
    __syncthreads();
#pragma unroll
    for (int i = 0; i < 32; i += 8)
        dst[(size_t)(c0 + ty + i) * R + r0 + tx] = tile[tx][ty + i];
}

// ---------------- x = in; xn = LN(x)*g --------------------------------------
__global__ __launch_bounds__(256)
void xinit_ln_k(const void* __restrict__ in, const void* __restrict__ g,
                const int* __restrict__ flag, float* __restrict__ x, bf16* __restrict__ xn)
{
    __shared__ float sm[4];
    int f = *flag;
    int row = blockIdx.x, t = threadIdx.x;
    float v0 = ldin(in, (size_t)row * 512 + t, f);
    float v1 = ldin(in, (size_t)row * 512 + t + 256, f);
    x[(size_t)row * 512 + t] = v0;
    x[(size_t)row * 512 + t + 256] = v1;
    float mean = block_sum(v0 + v1, sm) * (1.f / 512.f);
    float d0 = v0 - mean, d1 = v1 - mean;
    float var = block_sum(d0 * d0 + d1 * d1, sm) * (1.f / 512.f);
    float rstd = rsqrtf(var + 1e-5f);
    xn[(size_t)row * 512 + t]       = f2bf(d0 * rstd * ldin(g, t, f));
    xn[(size_t)row * 512 + t + 256] = f2bf(d1 * rstd * ldin(g, t + 256, f));
}

// ---------------- x += LN(t)*g1 ; xn = LN(x)*g2 ------------------------------
__global__ __launch_bounds__(256)
void addln_ln_k(const bf16* __restrict__ tin, const void* __restrict__ g1, int g1off,
                const void* __restrict__ g2, int g2off, const int* __restrict__ flag,
                float* __restrict__ x, bf16* __restrict__ xn)
{
    __shared__ float sm[4];
    int f = *flag;
    int row = blockIdx.x, t = threadIdx.x;
    const bf16* tr = tin + (size_t)row * 512;
    float v0 = bf2f(tr[t]), v1 = bf2f(tr[t + 256]);
    float mean = block_sum(v0 + v1, sm) * (1.f / 512.f);
    float d0 = v0 - mean, d1 = v1 - mean;
    float var = block_sum(d0 * d0 + d1 * d1, sm) * (1.f / 512.f);
    float rstd = rsqrtf(var + 1e-5f);
    float nx0 = x[(size_t)row * 512 + t]       + d0 * rstd * ldin(g1, g1off + t, f);
    float nx1 = x[(size_t)row * 512 + t + 256] + d1 * rstd * ldin(g1, g1off + t + 256, f);
    x[(size_t)row * 512 + t]       = nx0;
    x[(size_t)row * 512 + t + 256] = nx1;
    float mean2 = block_sum(nx0 + nx1, sm) * (1.f / 512.f);
    float e0 = nx0 - mean2, e1 = nx1 - mean2;
    float var2 = block_sum(e0 * e0 + e1 * e1, sm) * (1.f / 512.f);
    float rstd2 = rsqrtf(var2 + 1e-5f);
    xn[(size_t)row * 512 + t]       = f2bf(e0 * rstd2 * ldin(g2, g2off + t, f));
    xn[(size_t)row * 512 + t + 256] = f2bf(e1 * rstd2 * ldin(g2, g2off + t + 256, f));
}

// ---------------- x += t ; xn = (stable? stableLN : LN)(x)*g -----------------
__global__ __launch_bounds__(256)
void add_ln_k(const bf16* __restrict__ tin, const void* __restrict__ g, int goff,
              const int* __restrict__ flag, int stable,
              float* __restrict__ x, bf16* __restrict__ xn)
{
    __shared__ float sm[4];
    int f = *flag;
    int row = blockIdx.x, t = threadIdx.x;
    float nx0 = x[(size_t)row * 512 + t]       + bf2f(tin[(size_t)row * 512 + t]);
    float nx1 = x[(size_t)row * 512 + t + 256] + bf2f(tin[(size_t)row * 512 + t + 256]);
    x[(size_t)row * 512 + t]       = nx0;
    x[(size_t)row * 512 + t + 256] = nx1;
    float v0 = nx0, v1 = nx1;
    if (stable) {
        float mx = block_max(fmaxf(v0, v1), sm);
        v0 /= mx; v1 /= mx;
    }
    float mean = block_sum(v0 + v1, sm) * (1.f / 512.f);
    float d0 = v0 - mean, d1 = v1 - mean;
    float var = block_sum(d0 * d0 + d1 * d1, sm) * (1.f / 512.f);
    float rstd = rsqrtf(var + 1e-5f);
    xn[(size_t)row * 512 + t]       = f2bf(d0 * rstd * ldin(g, goff + t, f));
    xn[(size_t)row * 512 + t + 256] = f2bf(d1 * rstd * ldin(g, goff + t + 256, f));
}

// ---------------- silu gate --------------------------------------------------
__global__ __launch_bounds__(256)
void silu_k(bf16* __restrict__ u)
{
    size_t i = (size_t)blockIdx.x * 256 + threadIdx.x;
    size_t r = i >> 11;
    int c = (int)(i & 2047);
    float a = bf2f(u[r * 4096 + c]);
    float gg = bf2f(u[r * 4096 + 2048 + c]);
    u[r * 4096 + c] = f2bf(a * (gg / (1.f + expf(-gg))));
}

// ---------------- rel-pos bias table ----------------------------------------
__global__ __launch_bounds__(256)
void bias_k(const void* __restrict__ rpe, const int* __restrict__ flag, float* __restrict__ tab)
{
    int f = *flag;
    int idx = blockIdx.x * 256 + threadIdx.x;
    if (idx >= 8 * 1025) return;
    int h = idx / 1025, dist = idx % 1025;
    int bkt;
    if (dist < 16) bkt = dist;
    else {
        bkt = 16 + (int)(logf((float)dist / 16.f) / logf(8.f) * 16.f);
        if (bkt > 31) bkt = 31;
    }
    tab[idx] = ldin(rpe, bkt * 8 + h, f);
}

// ---------------- q prep (qkv stride 640) ------------------------------------
__global__ __launch_bounds__(256)
void qprep_k(const bf16* __restrict__ qkv, bf16* __restrict__ Q)
{
    int rid = blockIdx.x * 4 + (threadIdx.x >> 6);
    int lane = threadIdx.x & 63;
    int h = rid & 7;
    int n = (rid >> 3) & 1023;
    int b = rid >> 13;
    float v = bf2f(qkv[(size_t)((b << 10) | n) * 640 + h * 64 + lane]) * 16.f;
    if (lane < 32) {
        int p = lane >> 1;
        float ang = (float)n * expf((float)p * -0.5756462732f);
        float c = cosf(ang), s = sinf(ang);
        float other = __shfl_xor(v, 1, 64);
        float rot = (lane & 1) ? other : -other;
        v = v * c + rot * s;
    }
    float nrm = sqrtf(wave_sum(v * v));
    v = v / fmaxf(nrm, 1e-12f) * 4.f;
    Q[(((size_t)(b * 8 + h)) * 1024 + n) * 64 + lane] = f2bf(v);
}

// ---- k/v prep (qkv stride 640): K[b][j][d], Vt[b][d][j]; zero pad j>=1025 ---
__global__ __launch_bounds__(256)
void kvprep_k(const bf16* __restrict__ qkv, const void* __restrict__ nkv, int nkoff,
              const int* __restrict__ flag, bf16* __restrict__ K, bf16* __restrict__ Vt)
{
    int f = *flag;
    int rid = blockIdx.x * 4 + (threadIdx.x >> 6);
    if (rid >= 4 * 1088) return;
    int lane = threadIdx.x & 63;
    int j = rid % 1088;
    int b = rid / 1088;
    if (j >= 1025) {           // zero the padding so no ws read is ever stale
        K[((size_t)b * 1088 + j) * 64 + lane] = f2bf(0.f);
        Vt[((size_t)b * 64 + lane) * 1088 + j] = f2bf(0.f);
        return;
    }
    float kv, vv;
    if (j == 0) {
        kv = ldin(nkv, nkoff + lane, f);
        vv = ldin(nkv, nkoff + 64 + lane, f);
    } else {
        int n = j - 1;
        const bf16* src = qkv + (size_t)(b * 1024 + n) * 640 + 512;
        kv = bf2f(src[lane]);
        vv = bf2f(src[64 + lane]);
        if (lane < 32) {
            int p = lane >> 1;
            float ang = (float)n * expf((float)p * -0.5756462732f);
            float c = cosf(ang), s = sinf(ang);
            float other = __shfl_xor(kv, 1, 64);
            float rot = (lane & 1) ? other : -other;
            kv = kv * c + rot * s;
        }
    }
    float nrm = sqrtf(wave_sum(kv * kv));
    kv = kv / fmaxf(nrm, 1e-12f) * 4.f;
    K[((size_t)b * 1088 + j) * 64 + lane] = f2bf(kv);
    Vt[((size_t)b * 64 + lane) * 1088 + j] = f2bf(vv);
}

// ---------------- MFMA flash attention (R4-proven body, reversed-y) ----------
// grid (B*H, 16), block 256 = 4 waves; block handles 64 query rows.
__global__ __launch_bounds__(256)
void attn_mfma(const bf16* __restrict__ Q, const bf16* __restrict__ Kg,
               const bf16* __restrict__ Vtg, const float* __restrict__ bias,
               bf16* __restrict__ O)
{
    __shared__ bf16 Ks[64][72];
    __shared__ bf16 Vts[64][72];
    __shared__ bf16 Ps[4][16][72];
    const int bh = blockIdx.x, b = bh >> 3, h = bh & 7;
    const int yy = (int)gridDim.y - 1 - (int)blockIdx.y;   // longest first
    const int i0 = yy * 64;
    const int t = threadIdx.x, lane = t & 63, w = t >> 6;
    const int col = lane & 15, quad = lane >> 4, fk = quad * 8;
    const float* bt = bias + h * 1025;
    const bf16* Kb = Kg + (size_t)b * 1088 * 64;
    const bf16* Vb = Vtg + (size_t)b * 64 * 1088;

    v8bf qf[2];
    const bf16* qrow = Q + ((size_t)bh * 1024 + i0 + w * 16 + col) * 64;
    qf[0] = *(const v8bf*)(qrow + fk);
    qf[1] = *(const v8bf*)(qrow + 32 + fk);

    v4f oacc[4];
#pragma unroll
    for (int dt = 0; dt < 4; ++dt) { v4f z = {0.f,0.f,0.f,0.f}; oacc[dt] = z; }
    float m_run[4] = {-3e38f, -3e38f, -3e38f, -3e38f};
    float l_run[4] = {0.f, 0.f, 0.f, 0.f};

    const int nch = yy + 2;
    for (int ch = 0; ch < nch; ++ch) {
        const int j0 = ch * 64;
        __syncthreads();
#pragma unroll
        for (int rep = 0; rep < 2; ++rep) {
            int c = t + 256 * rep;
            int rr = c >> 3;
            int coff = (c & 7) * 8;
            *(v8bf*)(&Ks[rr][coff])  = *(const v8bf*)(Kb + (size_t)(j0 + rr) * 64 + coff);
            *(v8bf*)(&Vts[rr][coff]) = *(const v8bf*)(Vb + (size_t)rr * 1088 + j0 + coff);
        }
        __syncthreads();
        v4f sreg[4];
#pragma unroll
        for (int nt = 0; nt < 4; ++nt) {
            v4f z = {0.f,0.f,0.f,0.f};
            v8bf kf0 = *(const v8bf*)(&Ks[nt * 16 + col][fk]);
            v8bf kf1 = *(const v8bf*)(&Ks[nt * 16 + col][32 + fk]);
            z = __builtin_amdgcn_mfma_f32_16x16x32_bf16(qf[0], kf0, z, 0, 0, 0);
            z = __builtin_amdgcn_mfma_f32_16x16x32_bf16(qf[1], kf1, z, 0, 0, 0);
            sreg[nt] = z;
        }
        float p[4][4];
#pragma unroll
        for (int reg = 0; reg < 4; ++reg) {
            int i = i0 + w * 16 + quad * 4 + reg;
            float mx = -3e38f;
#pragma unroll
            for (int nt = 0; nt < 4; ++nt) {
                int j = j0 + nt * 16 + col;
                float s;
                if (j <= i + 1 && j < 1025) {
                    int dist = i - j; if (dist < 0) dist = 0;
                    s = sreg[nt][reg] + bt[dist];
                } else s = -1e30f;
                sreg[nt][reg] = s;
                mx = fmaxf(mx, s);
            }
#pragma unroll
            for (int o = 1; o < 16; o <<= 1) mx = fmaxf(mx, __shfl_xor(mx, o, 64));
            float mnew = fmaxf(m_run[reg], mx);
            float alpha = expf(m_run[reg] - mnew);
            float ls = 0.f;
#pragma unroll
            for (int nt = 0; nt < 4; ++nt) {
                float pp = expf(sreg[nt][reg] - mnew);
                p[nt][reg] = pp;
                ls += pp;
            }
#pragma unroll
            for (int o = 1; o < 16; o <<= 1) ls += __shfl_xor(ls, o, 64);
            l_run[reg] = l_run[reg] * alpha + ls;
            m_run[reg] = mnew;
#pragma unroll
            for (int dt = 0; dt < 4; ++dt) oacc[dt][reg] *= alpha;
        }
#pragma unroll
        for (int reg = 0; reg < 4; ++reg) {
            int row = quad * 4 + reg;
#pragma unroll
            for (int nt = 0; nt < 4; ++nt)
                Ps[w][row][nt * 16 + col] = f2bf(p[nt][reg]);
        }
        v8bf pf[2];
        pf[0] = *(const v8bf*)(&Ps[w][col][fk]);
        pf[1] = *(const v8bf*)(&Ps[w][col][32 + fk]);
#pragma unroll
        for (int dt = 0; dt < 4; ++dt) {
#pragma unroll
            for (int ks = 0; ks < 2; ++ks) {
                v8bf vf = *(const v8bf*)(&Vts[dt * 16 + col][ks * 32 + fk]);
                oacc[dt] = __builtin_amdgcn_mfma_f32_16x16x32_bf16(pf[ks], vf, oacc[dt], 0, 0, 0);
            }
        }
    }
#pragma unroll
    for (int reg = 0; reg < 4; ++reg) {
        int i = i0 + w * 16 + quad * 4 + reg;
        float inv = 1.f / l_run[reg];
#pragma unroll
        for (int dt = 0; dt < 4; ++dt)
            O[((size_t)(b * 1024 + i)) * 512 + h * 64 + dt * 16 + col] =
                f2bf(oacc[dt][reg] * inv);
    }
}

// =============================================================================
extern "C" void kernel_launch(void* const* d_in, const int* in_sizes, int n_in,
                              void* d_out, int out_size, void* d_ws, size_t ws_size,
                              hipStream_t stream)
{
    const void* x_in     = d_in[0];
    const void* rpe      = d_in[1];
    const void* g_attn   = d_in[2];
    const void* null_kv  = d_in[3];
    const void* Wq       = d_in[4];
    const void* Wkv      = d_in[5];
    const void* Wo       = d_in[6];
    const void* g_attn_o = d_in[7];
    const void* g_ff     = d_in[8];
    const void* W1       = d_in[9];
    const void* W2       = d_in[10];
    const void* g_final  = d_in[11];
    const void* W_proj   = d_in[12];

    char* wp = (char*)d_ws;
    auto alloc = [&](size_t bytes) {
        char* p = wp; wp += (bytes + 255) & ~(size_t)255; return p;
    };
    float* xf    = (float*)alloc(4096ull * 512 * 4);
    bf16*  xn    = (bf16*) alloc(4096ull * 512 * 2);
    bf16*  tb    = (bf16*) alloc(4096ull * 512 * 2);
    bf16*  ub    = (bf16*) alloc(4096ull * 4096 * 2);
    bf16*  Kb    = (bf16*) alloc(4ull * 1088 * 64 * 2);
    bf16*  Vtb   = (bf16*) alloc(4ull * 64 * 1088 * 2);
    float* btab  = (float*)alloc(8ull * 1025 * 4);
    int*   dfl   = (int*)  alloc(256);
    bf16*  WqkvT = (bf16*) alloc(6ull * 640 * 512 * 2);
    bf16*  WoT   = (bf16*) alloc(6ull * 512 * 512 * 2);
    bf16*  W1T   = (bf16*) alloc(6ull * 4096 * 512 * 2);
    bf16*  W2T   = (bf16*) alloc(6ull * 512 * 2048 * 2);
    bf16*  WpT   = (bf16*) alloc(512ull * 512 * 2);
    bf16*  qkvb  = ub;                       // 4096*640
    bf16*  Qb    = ub + 2621440;             // 4096*512
    bf16*  ob    = ub + 2621440 + 2097152;   // 4096*512

    detect_k<<<1, 256, 0, stream>>>((const unsigned short*)x_in, dfl);
    transpose2_k<<<dim3(16, 16, 6),  dim3(32, 8), 0, stream>>>(Wq, WqkvT, 512, 512, 512ull*512, 640ull*512, dfl);
    transpose2_k<<<dim3(4, 16, 6),   dim3(32, 8), 0, stream>>>(Wkv, WqkvT + 512ull*512, 512, 128, 512ull*128, 640ull*512, dfl);
    transpose2_k<<<dim3(16, 16, 6),  dim3(32, 8), 0, stream>>>(Wo, WoT, 512, 512, 512ull*512, 512ull*512, dfl);
    transpose2_k<<<dim3(128, 16, 6), dim3(32, 8), 0, stream>>>(W1, W1T, 512, 4096, 512ull*4096, 512ull*4096, dfl);
    transpose2_k<<<dim3(16, 64, 6),  dim3(32, 8), 0, stream>>>(W2, W2T, 2048, 512, 2048ull*512, 2048ull*512, dfl);
    transpose2_k<<<dim3(16, 16, 1),  dim3(32, 8), 0, stream>>>(W_proj, WpT, 512, 512, 512ull*512, 512ull*512, dfl);
    bias_k<<<33, 256, 0, stream>>>(rpe, dfl, btab);
    xinit_ln_k<<<4096, 256, 0, stream>>>(x_in, g_attn, dfl, xf, xn);

    for (int l = 0; l < 6; ++l) {
        gemm64<<<dim3(64, 5), 256, 0, stream>>>(xn, WqkvT + (size_t)l * 640 * 512, qkvb, 4096, 640, 512, 512);
        qprep_k<<<8192, 256, 0, stream>>>(qkvb, Qb);
        kvprep_k<<<1088, 256, 0, stream>>>(qkvb, null_kv, l * 128, dfl, Kb, Vtb);
        attn_mfma<<<dim3(32, 16), 256, 0, stream>>>(Qb, Kb, Vtb, btab, ob);
        gemm64<<<dim3(64, 4), 256, 0, stream>>>(ob, WoT + (size_t)l * 512 * 512, tb, 4096, 512, 512, 512);
        addln_ln_k<<<4096, 256, 0, stream>>>(tb, g_attn_o, l * 512, g_ff, l * 512, dfl, xf, xn);
        gemm_bt<<<dim3(32, 32), 256, 0, stream>>>(xn, W1T + (size_t)l * 4096 * 512, ub, 4096, 4096, 512, 512);
        silu_k<<<32768, 256, 0, stream>>>(ub);
        gemm64<<<dim3(64, 4), 256, 0, stream>>>(ub, W2T + (size_t)l * 512 * 2048, tb, 4096, 512, 2048, 4096);
        if (l < 5)
            add_ln_k<<<4096, 256, 0, stream>>>(tb, g_attn, (l + 1) * 512, dfl, 0, xf, xn);
        else
            add_ln_k<<<4096, 256, 0, stream>>>(tb, g_final, 0, dfl, 1, xf, xn);
    }
    gemm64_out<<<dim3(64, 4), 256, 0, stream>>>(xn, WpT, d_out, 4096, 512, 512, 512, dfl);
}

// Round 7
// 1252.520 us; speedup vs baseline: 2.0816x; 1.1600x over previous
//
#include <hip/hip_runtime.h>
#include <hip/hip_bf16.h>
#include <cmath>

using bf16 = __hip_bfloat16;
typedef __bf16 v8bf __attribute__((ext_vector_type(8)));
typedef float  v4f  __attribute__((ext_vector_type(4)));

__device__ __forceinline__ float bf2f(bf16 x) { return __bfloat162float(x); }
__device__ __forceinline__ bf16  f2bf(float x) { return __float2bfloat16(x); }

// async global->LDS, 16B per lane (lds dest = wave-uniform base + lane*16)
__device__ __forceinline__ void gll16(const bf16* g, bf16* l) {
    __builtin_amdgcn_global_load_lds(
        (const __attribute__((address_space(1))) unsigned int*)g,
        (__attribute__((address_space(3))) unsigned int*)l, 16, 0, 0);
}

__device__ __forceinline__ float ldin(const void* p, size_t i, int isf32) {
    if (isf32) return ((const float*)p)[i];
    return bf2f(((const bf16*)p)[i]);
}

__device__ __forceinline__ float wave_sum(float v) {
#pragma unroll
    for (int o = 32; o > 0; o >>= 1) v += __shfl_xor(v, o, 64);
    return v;
}
__device__ __forceinline__ float wave_max(float v) {
#pragma unroll
    for (int o = 32; o > 0; o >>= 1) v = fmaxf(v, __shfl_xor(v, o, 64));
    return v;
}
__device__ __forceinline__ float block_sum(float v, float* sm) {
    v = wave_sum(v);
    int lane = threadIdx.x & 63, w = threadIdx.x >> 6;
    __syncthreads();
    if (lane == 0) sm[w] = v;
    __syncthreads();
    return (sm[0] + sm[1]) + (sm[2] + sm[3]);
}
__device__ __forceinline__ float block_max(float v, float* sm) {
    v = wave_max(v);
    int lane = threadIdx.x & 63, w = threadIdx.x >> 6;
    __syncthreads();
    if (lane == 0) sm[w] = v;
    __syncthreads();
    return fmaxf(fmaxf(sm[0], sm[1]), fmaxf(sm[2], sm[3]));
}

// ---------------- dtype detector -------------------------------------------
__global__ void detect_k(const unsigned short* __restrict__ x, int* __restrict__ flag)
{
    __shared__ int s;
    int t = threadIdx.x;
    if (t == 0) s = 0;
    __syncthreads();
    int bad = 0;
    for (int i = t; i < 4096; i += 256) {
        int e = (x[i] >> 7) & 0xFF;
        if (e >= 147) bad++;
    }
    atomicAdd(&s, bad);
    __syncthreads();
    if (t == 0) *flag = (s > 64) ? 1 : 0;
}

// ---------------- MFMA GEMM 128x128 (async LDS staging) ----------------------
__global__ __launch_bounds__(256)
void gemm_bt(const bf16* __restrict__ A, const bf16* __restrict__ BT,
             bf16* __restrict__ C, int M, int N, int K, int lda)
{
    __shared__ bf16 As[128 * 32];
    __shared__ bf16 Bs[128 * 32];
    const int t = threadIdx.x;
    const int lane = t & 63;
    const int wave = t >> 6;
    const int wm = (wave >> 1) * 64;
    const int wn = (wave & 1) * 64;
    const int bm = blockIdx.x * 128;
    const int bn = blockIdx.y * 128;
    const int fr = lane & 15;
    const int fk = (lane >> 4) * 8;

    v4f acc[4][4];
#pragma unroll
    for (int i = 0; i < 4; ++i)
#pragma unroll
        for (int j = 0; j < 4; ++j) { v4f z = {0.f, 0.f, 0.f, 0.f}; acc[i][j] = z; }

    for (int k0 = 0; k0 < K; k0 += 32) {
#pragma unroll
        for (int r = 0; r < 2; ++r) {
            int c = t + 256 * r;
            int row = c >> 2;
            int koff = (c & 3) * 8;
            gll16(A + (size_t)(bm + row) * lda + k0 + koff, &As[c * 8]);
            gll16(BT + (size_t)(bn + row) * K + k0 + koff, &Bs[c * 8]);
        }
        __syncthreads();
        v8bf af[4], bfr[4];
#pragma unroll
        for (int mt = 0; mt < 4; ++mt)
            af[mt] = *(const v8bf*)(&As[(wm + mt * 16 + fr) * 32 + fk]);
#pragma unroll
        for (int nt = 0; nt < 4; ++nt)
            bfr[nt] = *(const v8bf*)(&Bs[(wn + nt * 16 + fr) * 32 + fk]);
#pragma unroll
        for (int mt = 0; mt < 4; ++mt)
#pragma unroll
            for (int nt = 0; nt < 4; ++nt)
                acc[mt][nt] = __builtin_amdgcn_mfma_f32_16x16x32_bf16(
                    af[mt], bfr[nt], acc[mt][nt], 0, 0, 0);
        __syncthreads();
    }
    const int r0 = (lane >> 4) * 4;
#pragma unroll
    for (int mt = 0; mt < 4; ++mt)
#pragma unroll
        for (int nt = 0; nt < 4; ++nt)
#pragma unroll
            for (int r = 0; r < 4; ++r) {
                int row = bm + wm + mt * 16 + r0 + r;
                int col = bn + wn + nt * 16 + fr;
                C[(size_t)row * N + col] = f2bf(acc[mt][nt][r]);
            }
}

// ---------------- MFMA GEMM 64x128 tile (async LDS staging) ------------------
__global__ __launch_bounds__(256)
void gemm64(const bf16* __restrict__ A, const bf16* __restrict__ BT,
            bf16* __restrict__ C, int M, int N, int K, int lda)
{
    __shared__ bf16 As[64 * 32];
    __shared__ bf16 Bs[128 * 32];
    const int t = threadIdx.x;
    const int lane = t & 63;
    const int wave = t >> 6;
    const int wm = (wave >> 1) * 32;
    const int wn = (wave & 1) * 64;
    const int bm = blockIdx.x * 64;
    const int bn = blockIdx.y * 128;
    const int fr = lane & 15;
    const int fk = (lane >> 4) * 8;

    v4f acc[2][4];
#pragma unroll
    for (int i = 0; i < 2; ++i)
#pragma unroll
        for (int j = 0; j < 4; ++j) { v4f z = {0.f, 0.f, 0.f, 0.f}; acc[i][j] = z; }

    for (int k0 = 0; k0 < K; k0 += 32) {
        {
            int row = t >> 2, koff = (t & 3) * 8;
            gll16(A + (size_t)(bm + row) * lda + k0 + koff, &As[t * 8]);
        }
#pragma unroll
        for (int r = 0; r < 2; ++r) {
            int c = t + 256 * r;
            int row = c >> 2, koff = (c & 3) * 8;
            gll16(BT + (size_t)(bn + row) * K + k0 + koff, &Bs[c * 8]);
        }
        __syncthreads();
        v8bf af[2], bfr[4];
#pragma unroll
        for (int mt = 0; mt < 2; ++mt)
            af[mt] = *(const v8bf*)(&As[(wm + mt * 16 + fr) * 32 + fk]);
#pragma unroll
        for (int nt = 0; nt < 4; ++nt)
            bfr[nt] = *(const v8bf*)(&Bs[(wn + nt * 16 + fr) * 32 + fk]);
#pragma unroll
        for (int mt = 0; mt < 2; ++mt)
#pragma unroll
            for (int nt = 0; nt < 4; ++nt)
                acc[mt][nt] = __builtin_amdgcn_mfma_f32_16x16x32_bf16(
                    af[mt], bfr[nt], acc[mt][nt], 0, 0, 0);
        __syncthreads();
    }
    const int r0 = (lane >> 4) * 4;
#pragma unroll
    for (int mt = 0; mt < 2; ++mt)
#pragma unroll
        for (int nt = 0; nt < 4; ++nt)
#pragma unroll
            for (int r = 0; r < 4; ++r) {
                int row = bm + wm + mt * 16 + r0 + r;
                int col = bn + wn + nt * 16 + fr;
                C[(size_t)row * N + col] = f2bf(acc[mt][nt][r]);
            }
}

// ---- gemm64 with flag-selected output dtype (final projection) --------------
__global__ __launch_bounds__(256)
void gemm64_out(const bf16* __restrict__ A, const bf16* __restrict__ BT,
                void* __restrict__ C, int M, int N, int K, int lda,
                const int* __restrict__ flag)
{
    __shared__ bf16 As[64 * 32];
    __shared__ bf16 Bs[128 * 32];
    const int f = *flag;
    const int t = threadIdx.x;
    const int lane = t & 63;
    const int wave = t >> 6;
    const int wm = (wave >> 1) * 32;
    const int wn = (wave & 1) * 64;
    const int bm = blockIdx.x * 64;
    const int bn = blockIdx.y * 128;
    const int fr = lane & 15;
    const int fk = (lane >> 4) * 8;

    v4f acc[2][4];
#pragma unroll
    for (int i = 0; i < 2; ++i)
#pragma unroll
        for (int j = 0; j < 4; ++j) { v4f z = {0.f, 0.f, 0.f, 0.f}; acc[i][j] = z; }

    for (int k0 = 0; k0 < K; k0 += 32) {
        {
            int row = t >> 2, koff = (t & 3) * 8;
            gll16(A + (size_t)(bm + row) * lda + k0 + koff, &As[t * 8]);
        }
#pragma unroll
        for (int r = 0; r < 2; ++r) {
            int c = t + 256 * r;
            int row = c >> 2, koff = (c & 3) * 8;
            gll16(BT + (size_t)(bn + row) * K + k0 + koff, &Bs[c * 8]);
        }
        __syncthreads();
        v8bf af[2], bfr[4];
#pragma unroll
        for (int mt = 0; mt < 2; ++mt)
            af[mt] = *(const v8bf*)(&As[(wm + mt * 16 + fr) * 32 + fk]);
#pragma unroll
        for (int nt = 0; nt < 4; ++nt)
            bfr[nt] = *(const v8bf*)(&Bs[(wn + nt * 16 + fr) * 32 + fk]);
#pragma unroll
        for (int mt = 0; mt < 2; ++mt)
#pragma unroll
            for (int nt = 0; nt < 4; ++nt)
                acc[mt][nt] = __builtin_amdgcn_mfma_f32_16x16x32_bf16(
                    af[mt], bfr[nt], acc[mt][nt], 0, 0, 0);
        __syncthreads();
    }
    const int r0 = (lane >> 4) * 4;
#pragma unroll
    for (int mt = 0; mt < 2; ++mt)
#pragma unroll
        for (int nt = 0; nt < 4; ++nt)
#pragma unroll
            for (int r = 0; r < 4; ++r) {
                int row = bm + wm + mt * 16 + r0 + r;
                int col = bn + wn + nt * 16 + fr;
                if (f) ((float*)C)[(size_t)row * N + col] = acc[mt][nt][r];
                else   ((bf16*)C)[(size_t)row * N + col] = f2bf(acc[mt][nt][r]);
            }
}

// ---------------- transpose w/ separate z-strides ----------------------------
__global__ __launch_bounds__(256)
void transpose2_k(const void* __restrict__ in, bf16* __restrict__ out, int R, int C,
                  size_t inZ, size_t outZ, const int* __restrict__ flag)
{
    __shared__ bf16 tile[32][33];
    int f = *flag;
    size_t ioff = (size_t)blockIdx.z * inZ;
    bf16* dst = out + (size_t)blockIdx.z * outZ;
    int c0 = blockIdx.x * 32, r0 = blockIdx.y * 32;
    int tx = threadIdx.x, ty = threadIdx.y;
#pragma unroll
    for (int i = 0; i < 32; i += 8)
        tile[ty + i][tx] = f2bf(ldin(in, ioff + (size_t)(r0 + ty + i) * C + c0 + tx, f));
    __syncthreads();
#pragma unroll
    for (int i = 0; i < 32; i += 8)
        dst[(size_t)(c0 + ty + i) * R + r0 + tx] = tile[tx][ty + i];
}

// ---------------- x = in; xn = LN(x)*g --------------------------------------
__global__ __launch_bounds__(256)
void xinit_ln_k(const void* __restrict__ in, const void* __restrict__ g,
                const int* __restrict__ flag, float* __restrict__ x, bf16* __restrict__ xn)
{
    __shared__ float sm[4];
    int f = *flag;
    int row = blockIdx.x, t = threadIdx.x;
    float v0 = ldin(in, (size_t)row * 512 + t, f);
    float v1 = ldin(in, (size_t)row * 512 + t + 256, f);
    x[(size_t)row * 512 + t] = v0;
    x[(size_t)row * 512 + t + 256] = v1;
    float mean = block_sum(v0 + v1, sm) * (1.f / 512.f);
    float d0 = v0 - mean, d1 = v1 - mean;
    float var = block_sum(d0 * d0 + d1 * d1, sm) * (1.f / 512.f);
    float rstd = rsqrtf(var + 1e-5f);
    xn[(size_t)row * 512 + t]       = f2bf(d0 * rstd * ldin(g, t, f));
    xn[(size_t)row * 512 + t + 256] = f2bf(d1 * rstd * ldin(g, t + 256, f));
}

// ---------------- x += LN(t)*g1 ; xn = LN(x)*g2 ------------------------------
__global__ __launch_bounds__(256)
void addln_ln_k(const bf16* __restrict__ tin, const void* __restrict__ g1, int g1off,
                const void* __restrict__ g2, int g2off, const int* __restrict__ flag,
                float* __restrict__ x, bf16* __restrict__ xn)
{
    __shared__ float sm[4];
    int f = *flag;
    int row = blockIdx.x, t = threadIdx.x;
    const bf16* tr = tin + (size_t)row * 512;
    float v0 = bf2f(tr[t]), v1 = bf2f(tr[t + 256]);
    float mean = block_sum(v0 + v1, sm) * (1.f / 512.f);
    float d0 = v0 - mean, d1 = v1 - mean;
    float var = block_sum(d0 * d0 + d1 * d1, sm) * (1.f / 512.f);
    float rstd = rsqrtf(var + 1e-5f);
    float nx0 = x[(size_t)row * 512 + t]       + d0 * rstd * ldin(g1, g1off + t, f);
    float nx1 = x[(size_t)row * 512 + t + 256] + d1 * rstd * ldin(g1, g1off + t + 256, f);
    x[(size_t)row * 512 + t]       = nx0;
    x[(size_t)row * 512 + t + 256] = nx1;
    float mean2 = block_sum(nx0 + nx1, sm) * (1.f / 512.f);
    float e0 = nx0 - mean2, e1 = nx1 - mean2;
    float var2 = block_sum(e0 * e0 + e1 * e1, sm) * (1.f / 512.f);
    float rstd2 = rsqrtf(var2 + 1e-5f);
    xn[(size_t)row * 512 + t]       = f2bf(e0 * rstd2 * ldin(g2, g2off + t, f));
    xn[(size_t)row * 512 + t + 256] = f2bf(e1 * rstd2 * ldin(g2, g2off + t + 256, f));
}

// ---------------- x += t ; xn = (stable? stableLN : LN)(x)*g -----------------
__global__ __launch_bounds__(256)
void add_ln_k(const bf16* __restrict__ tin, const void* __restrict__ g, int goff,
              const int* __restrict__ flag, int stable,
              float* __restrict__ x, bf16* __restrict__ xn)
{
    __shared__ float sm[4];
    int f = *flag;
    int row = blockIdx.x, t = threadIdx.x;
    float nx0 = x[(size_t)row * 512 + t]       + bf2f(tin[(size_t)row * 512 + t]);
    float nx1 = x[(size_t)row * 512 + t + 256] + bf2f(tin[(size_t)row * 512 + t + 256]);
    x[(size_t)row * 512 + t]       = nx0;
    x[(size_t)row * 512 + t + 256] = nx1;
    float v0 = nx0, v1 = nx1;
    if (stable) {
        float mx = block_max(fmaxf(v0, v1), sm);
        v0 /= mx; v1 /= mx;
    }
    float mean = block_sum(v0 + v1, sm) * (1.f / 512.f);
    float d0 = v0 - mean, d1 = v1 - mean;
    float var = block_sum(d0 * d0 + d1 * d1, sm) * (1.f / 512.f);
    float rstd = rsqrtf(var + 1e-5f);
    xn[(size_t)row * 512 + t]       = f2bf(d0 * rstd * ldin(g, goff + t, f));
    xn[(size_t)row * 512 + t + 256] = f2bf(d1 * rstd * ldin(g, goff + t + 256, f));
}

// ---------------- silu gate --------------------------------------------------
__global__ __launch_bounds__(256)
void silu_k(bf16* __restrict__ u)
{
    size_t i = (size_t)blockIdx.x * 256 + threadIdx.x;
    size_t r = i >> 11;
    int c = (int)(i & 2047);
    float a = bf2f(u[r * 4096 + c]);
    float gg = bf2f(u[r * 4096 + 2048 + c]);
    u[r * 4096 + c] = f2bf(a * (gg / (1.f + expf(-gg))));
}

// ---------------- rel-pos bias table ----------------------------------------
__global__ __launch_bounds__(256)
void bias_k(const void* __restrict__ rpe, const int* __restrict__ flag, float* __restrict__ tab)
{
    int f = *flag;
    int idx = blockIdx.x * 256 + threadIdx.x;
    if (idx >= 8 * 1025) return;
    int h = idx / 1025, dist = idx % 1025;
    int bkt;
    if (dist < 16) bkt = dist;
    else {
        bkt = 16 + (int)(logf((float)dist / 16.f) / logf(8.f) * 16.f);
        if (bkt > 31) bkt = 31;
    }
    tab[idx] = ldin(rpe, bkt * 8 + h, f);
}

// ---------------- q prep (qkv stride 640) ------------------------------------
__global__ __launch_bounds__(256)
void qprep_k(const bf16* __restrict__ qkv, bf16* __restrict__ Q)
{
    int rid = blockIdx.x * 4 + (threadIdx.x >> 6);
    int lane = threadIdx.x & 63;
    int h = rid & 7;
    int n = (rid >> 3) & 1023;
    int b = rid >> 13;
    float v = bf2f(qkv[(size_t)((b << 10) | n) * 640 + h * 64 + lane]) * 16.f;
    if (lane < 32) {
        int p = lane >> 1;
        float ang = (float)n * expf((float)p * -0.5756462732f);
        float c = cosf(ang), s = sinf(ang);
        float other = __shfl_xor(v, 1, 64);
        float rot = (lane & 1) ? other : -other;
        v = v * c + rot * s;
    }
    float nrm = sqrtf(wave_sum(v * v));
    v = v / fmaxf(nrm, 1e-12f) * 4.f;
    Q[(((size_t)(b * 8 + h)) * 1024 + n) * 64 + lane] = f2bf(v);
}

// ---- k/v prep (qkv stride 640): K[b][j][d], Vt[b][d][j]; zero pad j>=1025 ---
__global__ __launch_bounds__(256)
void kvprep_k(const bf16* __restrict__ qkv, const void* __restrict__ nkv, int nkoff,
              const int* __restrict__ flag, bf16* __restrict__ K, bf16* __restrict__ Vt)
{
    int f = *flag;
    int rid = blockIdx.x * 4 + (threadIdx.x >> 6);
    if (rid >= 4 * 1088) return;
    int lane = threadIdx.x & 63;
    int j = rid % 1088;
    int b = rid / 1088;
    if (j >= 1025) {
        K[((size_t)b * 1088 + j) * 64 + lane] = f2bf(0.f);
        Vt[((size_t)b * 64 + lane) * 1088 + j] = f2bf(0.f);
        return;
    }
    float kv, vv;
    if (j == 0) {
        kv = ldin(nkv, nkoff + lane, f);
        vv = ldin(nkv, nkoff + 64 + lane, f);
    } else {
        int n = j - 1;
        const bf16* src = qkv + (size_t)(b * 1024 + n) * 640 + 512;
        kv = bf2f(src[lane]);
        vv = bf2f(src[64 + lane]);
        if (lane < 32) {
            int p = lane >> 1;
            float ang = (float)n * expf((float)p * -0.5756462732f);
            float c = cosf(ang), s = sinf(ang);
            float other = __shfl_xor(kv, 1, 64);
            float rot = (lane & 1) ? other : -other;
            kv = kv * c + rot * s;
        }
    }
    float nrm = sqrtf(wave_sum(kv * kv));
    kv = kv / fmaxf(nrm, 1e-12f) * 4.f;
    K[((size_t)b * 1088 + j) * 64 + lane] = f2bf(kv);
    Vt[((size_t)b * 64 + lane) * 1088 + j] = f2bf(vv);
}

// ---------------- MFMA flash attention, K-SPLIT (S=4) ------------------------
// grid (B*H=32, 16 qtiles, 4 splits), block 256 = 4 waves (16 q-rows each).
// Split s handles chunks s, s+4, ... of nch = yy+2. Emits UNNORMALIZED partial
// O (at scale m_s) + (m_s, l_s) per row. Combine kernel merges.
__global__ __launch_bounds__(256)
void attn_mfma(const bf16* __restrict__ Q, const bf16* __restrict__ Kg,
               const bf16* __restrict__ Vtg, const float* __restrict__ bias,
               bf16* __restrict__ Op, float* __restrict__ ml)
{
    __shared__ bf16 Ks[64][72];
    __shared__ bf16 Vts[64][72];
    __shared__ bf16 Ps[4][16][72];
    const int bh = blockIdx.x, b = bh >> 3, h = bh & 7;
    const int yy = (int)gridDim.y - 1 - (int)blockIdx.y;   // longest first
    const int sp = blockIdx.z;
    const int i0 = yy * 64;
    const int t = threadIdx.x, lane = t & 63, w = t >> 6;
    const int col = lane & 15, quad = lane >> 4, fk = quad * 8;
    const float* bt = bias + h * 1025;
    const bf16* Kb = Kg + (size_t)b * 1088 * 64;
    const bf16* Vb = Vtg + (size_t)b * 64 * 1088;

    v8bf qf[2];
    const bf16* qrow = Q + ((size_t)bh * 1024 + i0 + w * 16 + col) * 64;
    qf[0] = *(const v8bf*)(qrow + fk);
    qf[1] = *(const v8bf*)(qrow + 32 + fk);

    v4f oacc[4];
#pragma unroll
    for (int dt = 0; dt < 4; ++dt) { v4f z = {0.f,0.f,0.f,0.f}; oacc[dt] = z; }
    float m_run[4] = {-3e38f, -3e38f, -3e38f, -3e38f};
    float l_run[4] = {0.f, 0.f, 0.f, 0.f};

    const int nch = yy + 2;
    for (int ch = sp; ch < nch; ch += 4) {
        const int j0 = ch * 64;
        __syncthreads();
#pragma unroll
        for (int rep = 0; rep < 2; ++rep) {
            int c = t + 256 * rep;
            int rr = c >> 3;
            int coff = (c & 7) * 8;
            *(v8bf*)(&Ks[rr][coff])  = *(const v8bf*)(Kb + (size_t)(j0 + rr) * 64 + coff);
            *(v8bf*)(&Vts[rr][coff]) = *(const v8bf*)(Vb + (size_t)rr * 1088 + j0 + coff);
        }
        __syncthreads();
        v4f sreg[4];
#pragma unroll
        for (int nt = 0; nt < 4; ++nt) {
            v4f z = {0.f,0.f,0.f,0.f};
            v8bf kf0 = *(const v8bf*)(&Ks[nt * 16 + col][fk]);
            v8bf kf1 = *(const v8bf*)(&Ks[nt * 16 + col][32 + fk]);
            z = __builtin_amdgcn_mfma_f32_16x16x32_bf16(qf[0], kf0, z, 0, 0, 0);
            z = __builtin_amdgcn_mfma_f32_16x16x32_bf16(qf[1], kf1, z, 0, 0, 0);
            sreg[nt] = z;
        }
        float p[4][4];
#pragma unroll
        for (int reg = 0; reg < 4; ++reg) {
            int i = i0 + w * 16 + quad * 4 + reg;
            float mx = -3e38f;
#pragma unroll
            for (int nt = 0; nt < 4; ++nt) {
                int j = j0 + nt * 16 + col;
                float s;
                if (j <= i + 1 && j < 1025) {
                    int dist = i - j; if (dist < 0) dist = 0;
                    s = sreg[nt][reg] + bt[dist];
                } else s = -1e30f;
                sreg[nt][reg] = s;
                mx = fmaxf(mx, s);
            }
#pragma unroll
            for (int o = 1; o < 16; o <<= 1) mx = fmaxf(mx, __shfl_xor(mx, o, 64));
            float mnew = fmaxf(m_run[reg], mx);
            float alpha = expf(m_run[reg] - mnew);
            float ls = 0.f;
#pragma unroll
            for (int nt = 0; nt < 4; ++nt) {
                float pp = expf(sreg[nt][reg] - mnew);
                p[nt][reg] = pp;
                ls += pp;
            }
#pragma unroll
            for (int o = 1; o < 16; o <<= 1) ls += __shfl_xor(ls, o, 64);
            l_run[reg] = l_run[reg] * alpha + ls;
            m_run[reg] = mnew;
#pragma unroll
            for (int dt = 0; dt < 4; ++dt) oacc[dt][reg] *= alpha;
        }
#pragma unroll
        for (int reg = 0; reg < 4; ++reg) {
            int row = quad * 4 + reg;
#pragma unroll
            for (int nt = 0; nt < 4; ++nt)
                Ps[w][row][nt * 16 + col] = f2bf(p[nt][reg]);
        }
        v8bf pf[2];
        pf[0] = *(const v8bf*)(&Ps[w][col][fk]);
        pf[1] = *(const v8bf*)(&Ps[w][col][32 + fk]);
#pragma unroll
        for (int dt = 0; dt < 4; ++dt) {
#pragma unroll
            for (int ks = 0; ks < 2; ++ks) {
                v8bf vf = *(const v8bf*)(&Vts[dt * 16 + col][ks * 32 + fk]);
                oacc[dt] = __builtin_amdgcn_mfma_f32_16x16x32_bf16(pf[ks], vf, oacc[dt], 0, 0, 0);
            }
        }
    }
    // write UNNORMALIZED partials: Op[((sp*32+bh)*1024+i)*64+d], ml[...*2+{0,1}]
#pragma unroll
    for (int reg = 0; reg < 4; ++reg) {
        int i = i0 + w * 16 + quad * 4 + reg;
        size_t rbase = ((size_t)(sp * 32 + bh) * 1024 + i);
#pragma unroll
        for (int dt = 0; dt < 4; ++dt)
            Op[rbase * 64 + dt * 16 + col] = f2bf(oacc[dt][reg]);
        if (col == 0) {
            ml[rbase * 2]     = m_run[reg];
            ml[rbase * 2 + 1] = l_run[reg];
        }
    }
}

// ---------------- combine 4 k-split partials --------------------------------
__global__ __launch_bounds__(256)
void attn_comb(const bf16* __restrict__ Op, const float* __restrict__ ml,
               bf16* __restrict__ O)
{
    int tid = blockIdx.x * 256 + threadIdx.x;   // 32*1024*64 = 2,097,152
    int d = tid & 63;
    int r = tid >> 6;                           // bh*1024 + i
    float m0 = ml[(size_t)r * 2],                m1 = ml[((size_t)32768 + r) * 2];
    float m2 = ml[((size_t)65536 + r) * 2],      m3 = ml[((size_t)98304 + r) * 2];
    float l0 = ml[(size_t)r * 2 + 1],            l1 = ml[((size_t)32768 + r) * 2 + 1];
    float l2 = ml[((size_t)65536 + r) * 2 + 1],  l3 = ml[((size_t)98304 + r) * 2 + 1];
    float ms = fmaxf(fmaxf(m0, m1), fmaxf(m2, m3));
    float w0 = expf(m0 - ms), w1 = expf(m1 - ms), w2 = expf(m2 - ms), w3 = expf(m3 - ms);
    float ls = w0 * l0 + w1 * l1 + w2 * l2 + w3 * l3;
    float o = w0 * bf2f(Op[(size_t)r * 64 + d])
            + w1 * bf2f(Op[((size_t)32768 + r) * 64 + d])
            + w2 * bf2f(Op[((size_t)65536 + r) * 64 + d])
            + w3 * bf2f(Op[((size_t)98304 + r) * 64 + d]);
    int bh = r >> 10, i = r & 1023, b = bh >> 3, h = bh & 7;
    O[((size_t)(b * 1024 + i)) * 512 + h * 64 + d] = f2bf(o / ls);
}

// =============================================================================
extern "C" void kernel_launch(void* const* d_in, const int* in_sizes, int n_in,
                              void* d_out, int out_size, void* d_ws, size_t ws_size,
                              hipStream_t stream)
{
    const void* x_in     = d_in[0];
    const void* rpe      = d_in[1];
    const void* g_attn   = d_in[2];
    const void* null_kv  = d_in[3];
    const void* Wq       = d_in[4];
    const void* Wkv      = d_in[5];
    const void* Wo       = d_in[6];
    const void* g_attn_o = d_in[7];
    const void* g_ff     = d_in[8];
    const void* W1       = d_in[9];
    const void* W2       = d_in[10];
    const void* g_final  = d_in[11];
    const void* W_proj   = d_in[12];

    char* wp = (char*)d_ws;
    auto alloc = [&](size_t bytes) {
        char* p = wp; wp += (bytes + 255) & ~(size_t)255; return p;
    };
    float* xf    = (float*)alloc(4096ull * 512 * 4);
    bf16*  xn    = (bf16*) alloc(4096ull * 512 * 2);
    bf16*  tb    = (bf16*) alloc(4096ull * 512 * 2);
    bf16*  ub    = (bf16*) alloc(4096ull * 4096 * 2);
    bf16*  Kb    = (bf16*) alloc(4ull * 1088 * 64 * 2);
    bf16*  Vtb   = (bf16*) alloc(4ull * 64 * 1088 * 2);
    float* btab  = (float*)alloc(8ull * 1025 * 4);
    int*   dfl   = (int*)  alloc(256);
    bf16*  WqkvT = (bf16*) alloc(6ull * 640 * 512 * 2);
    bf16*  WoT   = (bf16*) alloc(6ull * 512 * 512 * 2);
    bf16*  W1T   = (bf16*) alloc(6ull * 4096 * 512 * 2);
    bf16*  W2T   = (bf16*) alloc(6ull * 512 * 2048 * 2);
    bf16*  WpT   = (bf16*) alloc(512ull * 512 * 2);
    // aliased into ub (16,777,216 elems; lifetimes end before W1 gemm writes ub)
    bf16*  qkvb  = ub;                        // 2,621,440 elems
    bf16*  Qb    = ub + 2621440;              // 2,097,152
    bf16*  ob    = ub + 4718592;              // 2,097,152
    bf16*  Opart = ub + 6815744;              // 4*32*1024*64 = 8,388,608
    float* mlprt = (float*)(ub + 15204352);   // 262,144 floats = 524,288 elems

    detect_k<<<1, 256, 0, stream>>>((const unsigned short*)x_in, dfl);
    transpose2_k<<<dim3(16, 16, 6),  dim3(32, 8), 0, stream>>>(Wq, WqkvT, 512, 512, 512ull*512, 640ull*512, dfl);
    transpose2_k<<<dim3(4, 16, 6),   dim3(32, 8), 0, stream>>>(Wkv, WqkvT + 512ull*512, 512, 128, 512ull*128, 640ull*512, dfl);
    transpose2_k<<<dim3(16, 16, 6),  dim3(32, 8), 0, stream>>>(Wo, WoT, 512, 512, 512ull*512, 512ull*512, dfl);
    transpose2_k<<<dim3(128, 16, 6), dim3(32, 8), 0, stream>>>(W1, W1T, 512, 4096, 512ull*4096, 512ull*4096, dfl);
    transpose2_k<<<dim3(16, 64, 6),  dim3(32, 8), 0, stream>>>(W2, W2T, 2048, 512, 2048ull*512, 2048ull*512, dfl);
    transpose2_k<<<dim3(16, 16, 1),  dim3(32, 8), 0, stream>>>(W_proj, WpT, 512, 512, 512ull*512, 512ull*512, dfl);
    bias_k<<<33, 256, 0, stream>>>(rpe, dfl, btab);
    xinit_ln_k<<<4096, 256, 0, stream>>>(x_in, g_attn, dfl, xf, xn);

    for (int l = 0; l < 6; ++l) {
        gemm64<<<dim3(64, 5), 256, 0, stream>>>(xn, WqkvT + (size_t)l * 640 * 512, qkvb, 4096, 640, 512, 512);
        qprep_k<<<8192, 256, 0, stream>>>(qkvb, Qb);
        kvprep_k<<<1088, 256, 0, stream>>>(qkvb, null_kv, l * 128, dfl, Kb, Vtb);
        attn_mfma<<<dim3(32, 16, 4), 256, 0, stream>>>(Qb, Kb, Vtb, btab, Opart, mlprt);
        attn_comb<<<8192, 256, 0, stream>>>(Opart, mlprt, ob);
        gemm64<<<dim3(64, 4), 256, 0, stream>>>(ob, WoT + (size_t)l * 512 * 512, tb, 4096, 512, 512, 512);
        addln_ln_k<<<4096, 256, 0, stream>>>(tb, g_attn_o, l * 512, g_ff, l * 512, dfl, xf, xn);
        gemm_bt<<<dim3(32, 32), 256, 0, stream>>>(xn, W1T + (size_t)l * 4096 * 512, ub, 4096, 4096, 512, 512);
        silu_k<<<32768, 256, 0, stream>>>(ub);
        gemm64<<<dim3(64, 4), 256, 0, stream>>>(ub, W2T + (size_t)l * 512 * 2048, tb, 4096, 512, 2048, 4096);
        if (l < 5)
            add_ln_k<<<4096, 256, 0, stream>>>(tb, g_attn, (l + 1) * 512, dfl, 0, xf, xn);
        else
            add_ln_k<<<4096, 256, 0, stream>>>(tb, g_final, 0, dfl, 1, xf, xn);
    }
    gemm64_out<<<dim3(64, 4), 256, 0, stream>>>(xn, WpT, d_out, 4096, 512, 512, 512, dfl);
}